// Round 7
// baseline (221.247 us; speedup 1.0000x reference)
//
#include <hip/hip_runtime.h>
#include <cstdint>
#include <cstddef>

#define D_MODEL 1024
#define NHEADS  16
#define DK      64
#define SEQ     2048
#define NBATCH  2

#define NEG_BIG (-1e30f)

typedef __attribute__((ext_vector_type(8))) short bf16x8;
typedef __attribute__((ext_vector_type(4))) short bf16x4;
typedef __attribute__((ext_vector_type(4))) float f32x4;

#if defined(__AMDGCN__)
#define SETPRIO(p) __builtin_amdgcn_s_setprio(p)
#else
#define SETPRIO(p)
#endif

// Host pass: amdgcn builtins unavailable -> guard on __AMDGCN__.
__device__ inline f32x4 mfma16x16x16(bf16x4 a, bf16x4 b, f32x4 c) {
#if defined(__AMDGCN__)
# if __has_builtin(__builtin_amdgcn_mfma_f32_16x16x16_bf16)
  return __builtin_amdgcn_mfma_f32_16x16x16_bf16(a, b, c, 0, 0, 0);
# else
  return __builtin_amdgcn_mfma_f32_16x16x16bf16_1k(a, b, c, 0, 0, 0);
# endif
#else
  (void)a; (void)b;
  return c;
#endif
}

__device__ inline void gll16(const unsigned short* g, unsigned short* l) {
#if defined(__AMDGCN__)
  __builtin_amdgcn_global_load_lds(
      (const __attribute__((address_space(1))) void*)g,
      (__attribute__((address_space(3))) void*)l, 16, 0, 0);
#else
  (void)g; (void)l;
#endif
}

__device__ inline unsigned short f2bf(float f) {
  unsigned int u = __float_as_uint(f);
  u += 0x7fffu + ((u >> 16) & 1u);   // round-to-nearest-even
  return (unsigned short)(u >> 16);
}

// ---------------------------------------------------------------------------
// Per-block dtype sniff + convert-8-elements helper (shared by cvt2/cvt3).
// fp32 data: even-index shorts are mantissa noise -> ~48% hit e-field>=0x84;
// bf16 N(0,1)-scale data: ~0%. Threshold 64/1024 per block.
// ---------------------------------------------------------------------------
__device__ __forceinline__ void cvt_block(const void* src,
                                          unsigned short* dst, int i0) {
  const unsigned short* sp =
      (const unsigned short*)src + (size_t)i0 * 8 + threadIdx.x * 8;
  int cnt = 0;
#pragma unroll
  for (int j = 0; j < 8; j += 2) {
    const unsigned int u = sp[j];
    cnt += (((u >> 7) & 0xFFu) >= 0x84u) ? 1 : 0;
  }
  __shared__ int red[256];
  red[threadIdx.x] = cnt;
  __syncthreads();
  for (int s = 128; s > 0; s >>= 1) {
    if (threadIdx.x < s) red[threadIdx.x] += red[threadIdx.x + s];
    __syncthreads();
  }
  const bool isf32 = red[0] > 64;

  const int i = i0 + threadIdx.x;
  if (isf32) {
    const float4* s = (const float4*)src;
    float4 a = s[2 * i], b = s[2 * i + 1];
    uint4 r;
    r.x = (unsigned)f2bf(a.x) | ((unsigned)f2bf(a.y) << 16);
    r.y = (unsigned)f2bf(a.z) | ((unsigned)f2bf(a.w) << 16);
    r.z = (unsigned)f2bf(b.x) | ((unsigned)f2bf(b.y) << 16);
    r.w = (unsigned)f2bf(b.z) | ((unsigned)f2bf(b.w) << 16);
    ((uint4*)dst)[i] = r;
  } else {
    ((uint4*)dst)[i] = ((const uint4*)src)[i];
  }
}

// Two-buffer canonicalize (fallback path when workspace is tight).
__global__ __launch_bounds__(256) void cvt2_kernel(
    const void* __restrict__ srcA, unsigned short* __restrict__ dstA, int n8A,
    const void* __restrict__ srcB, unsigned short* __restrict__ dstB, int n8B) {
  const int bi = blockIdx.x;
  const int nblkA = n8A >> 8;
  (void)n8B;
  if (bi < nblkA) cvt_block(srcA, dstA, bi << 8);
  else            cvt_block(srcB, dstB, (bi - nblkA) << 8);
}

// Three-buffer canonicalize: x + wqkv + wo in ONE dispatch.
__global__ __launch_bounds__(256) void cvt3_kernel(
    const void* __restrict__ srcA, unsigned short* __restrict__ dstA, int n8A,
    const void* __restrict__ srcB, unsigned short* __restrict__ dstB, int n8B,
    const void* __restrict__ srcC, unsigned short* __restrict__ dstC) {
  const int bi = blockIdx.x;
  const int nblkA = n8A >> 8;
  const int nblkB = n8B >> 8;
  if (bi < nblkA)               cvt_block(srcA, dstA, bi << 8);
  else if (bi < nblkA + nblkB)  cvt_block(srcB, dstB, (bi - nblkA) << 8);
  else                          cvt_block(srcC, dstC, (bi - nblkA - nblkB) << 8);
}

// ---------------------------------------------------------------------------
// 128 x (NF*32) tile GEMM mainloop, transposed-C, BK=64, async staging with
// SOURCE-PERMUTED global_load_lds: lane fetches granule (t&7)^(row&7) so
// the fixed dest layout lands XOR-swizzled -> conflict-free b128 frag reads.
// LDS rows of 128B: As[128][64], Bs[NF*32][64] (bf16). 16 K-iterations.
// ---------------------------------------------------------------------------
template <int NF>
__device__ inline void gemm_bt_t(const unsigned short* __restrict__ A,
                                 const unsigned short* __restrict__ W,
                                 int m0, int n0,
                                 unsigned short* As, unsigned short* Bs,
                                 f32x4 (&acc)[NF][4]) {
  const int t    = threadIdx.x;
  const int lane = t & 63;
  const int w    = t >> 6;
  const int wm   = (w >> 1) * 64;        // token offset
  const int wn   = (w & 1) * (NF * 16);  // feature offset
  const int frow = lane & 15;
  const int q4   = lane >> 4;            // granule base (0..3)

  for (int ft = 0; ft < NF; ++ft)
    for (int tt = 0; tt < 4; ++tt)
      acc[ft][tt] = (f32x4){0.f, 0.f, 0.f, 0.f};

  const int srow  = t >> 3;         // 0..31 (row within 32-row chunk)
  const int gslot = t & 7;          // dest granule slot

  for (int k0 = 0; k0 < 1024; k0 += 64) {
    __syncthreads();
#pragma unroll
    for (int c = 0; c < 4; ++c) {   // A: 4 chunks x 32 rows
      const int row = c * 32 + srow;
      const int gsrc = gslot ^ (row & 7);
      gll16(A + (size_t)(m0 + row) * 1024 + k0 + gsrc * 8,
            As + ((size_t)t + 256 * c) * 8);
    }
#pragma unroll
    for (int c = 0; c < NF; ++c) {  // B: NF chunks x 32 rows
      const int row = c * 32 + srow;
      const int gsrc = gslot ^ (row & 7);
      gll16(W + (size_t)(n0 + row) * 1024 + k0 + gsrc * 8,
            Bs + ((size_t)t + 256 * c) * 8);
    }
    __syncthreads();

#pragma unroll
    for (int kk = 0; kk < 2; ++kk) {
      const int gg = q4 + kk * 4;   // wanted global granule
      bf16x8 xv[4], wv[NF];
#pragma unroll
      for (int tt = 0; tt < 4; ++tt) {
        const int row = wm + tt * 16 + frow;
        xv[tt] = *(const bf16x8*)(As + row * 64 + ((gg ^ (row & 7)) << 3));
      }
#pragma unroll
      for (int ft = 0; ft < NF; ++ft) {
        const int row = wn + ft * 16 + frow;
        wv[ft] = *(const bf16x8*)(Bs + row * 64 + ((gg ^ (row & 7)) << 3));
      }
#pragma unroll
      for (int ft = 0; ft < NF; ++ft)
#pragma unroll
        for (int tt = 0; tt < 4; ++tt)
          acc[ft][tt] = __builtin_amdgcn_mfma_f32_16x16x32_bf16(wv[ft], xv[tt],
                                                                acc[ft][tt], 0, 0, 0);
    }
  }
}

// ---------------------------------------------------------------------------
// Kernel 1: QKV projection + fused RoPE. 128x128 tile (NF=4), grid 768.
// XCD-aware swizzle (T1): lin%8 = XCD (round-robin dispatch assumption,
// perf-only). XCD c owns m-panels {4c..4c+3} (1 MB A working set <= 4 MB L2).
// ---------------------------------------------------------------------------
__global__ __launch_bounds__(256) void qkv_rope_kernel(
    const unsigned short* __restrict__ x,
    const unsigned short* __restrict__ wqkv,
    unsigned short* __restrict__ Qw, unsigned short* __restrict__ Kw,
    unsigned short* __restrict__ Vw) {
  __shared__ __align__(16) unsigned short As[128 * 64];
  __shared__ __align__(16) unsigned short Bs[128 * 64];
  f32x4 acc[4][4];
  const int lin = blockIdx.y * 32 + blockIdx.x;   // 0..767
  const int c8  = lin & 7;                        // XCD (round-robin)
  const int i   = lin >> 3;                       // 0..95
  const int m0  = (c8 * 4 + (i & 3)) * 128;       // bijective remap
  const int n0  = (i >> 2) * 128;
  gemm_bt_t<4>(x, wqkv, m0, n0, As, Bs, acc);

  const int t = threadIdx.x, lane = t & 63, w = t >> 6;
  const int wm = (w >> 1) * 64, wn = (w & 1) * 64;
  const int i16 = lane & 15, q4 = lane >> 4;
  const int part = n0 >> 10;               // block-uniform
  unsigned short* dst = (part == 0) ? Qw : ((part == 1) ? Kw : Vw);
  const float LN_THETA_OVER_HALF = 0.2878231366242558f;  // ln(10000)/32

#pragma unroll
  for (int ft = 0; ft < 4; ++ft) {
    const int nb0 = n0 + wn + ft * 16 + (q4 << 2);  // 4 consecutive features
    const int h  = (nb0 >> 6) & 15;
    const int d0 = nb0 & 63;
    const float invf0 = __expf(-(float)(d0 >> 1) * LN_THETA_OVER_HALF);
    const float invf1 = __expf(-(float)((d0 >> 1) + 1) * LN_THETA_OVER_HALF);
#pragma unroll
    for (int tt = 0; tt < 4; ++tt) {
      const int m = m0 + wm + tt * 16 + i16;
      const int b = m >> 11, s = m & 2047;
      float v0 = acc[ft][tt][0], v1 = acc[ft][tt][1];
      float v2 = acc[ft][tt][2], v3 = acc[ft][tt][3];
      if (part < 2) {
        float sn0, cs0, sn1, cs1;
        __sincosf((float)s * invf0, &sn0, &cs0);
        __sincosf((float)s * invf1, &sn1, &cs1);
        const float r0 = v0 * cs0 - v1 * sn0;
        const float r1 = v0 * sn0 + v1 * cs0;
        const float r2 = v2 * cs1 - v3 * sn1;
        const float r3 = v2 * sn1 + v3 * cs1;
        v0 = r0; v1 = r1; v2 = r2; v3 = r3;
        if (part == 0) { v0 *= 0.125f; v1 *= 0.125f; v2 *= 0.125f; v3 *= 0.125f; }
      }
      ushort4 pk;
      pk.x = f2bf(v0); pk.y = f2bf(v1); pk.z = f2bf(v2); pk.w = f2bf(v3);
      *(ushort4*)(dst + (((size_t)(b * NHEADS + h)) * SEQ + s) * DK + d0) = pk;
    }
  }
}

// ---------------------------------------------------------------------------
// Per-128-key attention step for one q-tile (S^T formulation, R8-verified).
// T5: s_setprio(1) around the MFMA clusters (S^T, PV). Side effect (R6
// measured): setprio scheduling boundaries cut VGPR 128 -> 92, making room
// for the T14 prefetch registers without crossing the 128 cliff.
// ---------------------------------------------------------------------------
__device__ __forceinline__ void attn_step(
    const unsigned short* Ks0, const unsigned short* Ks1,
    const unsigned short* Vt0, const unsigned short* Vt1,
    bf16x8 qf0, bf16x8 qf1, int i16, int q4, int w,
    int q0t, int kt2, bool domask,
    float& m_i, float& l_i, f32x4 o_acc[4]) {
  // ---- S^T for both halves ----
  f32x4 s_acc[2][4];
  SETPRIO(1);
#pragma unroll
  for (int u = 0; u < 2; ++u) {
    const unsigned short* Ksu = u ? Ks1 : Ks0;
#pragma unroll
    for (int mt = 0; mt < 4; ++mt) {
      const int key = mt * 16 + i16;
      const int k7 = key & 7;
      bf16x8 a0 = *(const bf16x8*)(Ksu + key * 64 + ((q4 ^ k7) << 3));
      bf16x8 a1 = *(const bf16x8*)(Ksu + key * 64 + (((4 + q4) ^ k7) << 3));
      f32x4 acc = (f32x4){0.f, 0.f, 0.f, 0.f};
      acc = __builtin_amdgcn_mfma_f32_16x16x32_bf16(a0, qf0, acc, 0, 0, 0);
      acc = __builtin_amdgcn_mfma_f32_16x16x32_bf16(a1, qf1, acc, 0, 0, 0);
      s_acc[u][mt] = acc;
    }
  }
  SETPRIO(0);

  // ---- causal mask on final pair of this tile (block-uniform branch) ----
  if (domask) {
    const int qrow = q0t + w * 16 + i16;
#pragma unroll
    for (int u = 0; u < 2; ++u) {
      const int kb2 = (kt2 + u) * 64 + q4 * 4;
#pragma unroll
      for (int mt = 0; mt < 4; ++mt)
#pragma unroll
        for (int r = 0; r < 4; ++r)
          if (kb2 + mt * 16 + r > qrow) s_acc[u][mt][r] = NEG_BIG;
    }
  }

  // ---- online softmax over 128 keys ----
  float tm = NEG_BIG;
#pragma unroll
  for (int u = 0; u < 2; ++u)
#pragma unroll
    for (int mt = 0; mt < 4; ++mt)
#pragma unroll
      for (int r = 0; r < 4; ++r) tm = fmaxf(tm, s_acc[u][mt][r]);
  tm = fmaxf(tm, __shfl_xor(tm, 16, 64));
  tm = fmaxf(tm, __shfl_xor(tm, 32, 64));
  const float m_new = fmaxf(m_i, tm);
  const float alpha = __expf(m_i - m_new);
  m_i = m_new;

  bf16x4 pf[2][4];
  float ls = 0.f;
#pragma unroll
  for (int u = 0; u < 2; ++u)
#pragma unroll
    for (int mt = 0; mt < 4; ++mt) {
      float p0 = __expf(s_acc[u][mt][0] - m_new);
      float p1 = __expf(s_acc[u][mt][1] - m_new);
      float p2 = __expf(s_acc[u][mt][2] - m_new);
      float p3 = __expf(s_acc[u][mt][3] - m_new);
      ls += (p0 + p1) + (p2 + p3);
      pf[u][mt][0] = (short)f2bf(p0);
      pf[u][mt][1] = (short)f2bf(p1);
      pf[u][mt][2] = (short)f2bf(p2);
      pf[u][mt][3] = (short)f2bf(p3);
    }
  ls += __shfl_xor(ls, 16, 64);
  ls += __shfl_xor(ls, 32, 64);
  l_i = l_i * alpha + ls;

  float a4[4];
#pragma unroll
  for (int r = 0; r < 4; ++r) a4[r] = __shfl(alpha, (q4 << 2) + r, 64);
#pragma unroll
  for (int n = 0; n < 4; ++n)
#pragma unroll
    for (int r = 0; r < 4; ++r) o_acc[n][r] *= a4[r];

  // ---- PV over both halves ----
  SETPRIO(1);
#pragma unroll
  for (int u = 0; u < 2; ++u) {
    const unsigned short* Vtu = u ? Vt1 : Vt0;
#pragma unroll
    for (int mt = 0; mt < 4; ++mt) {
#pragma unroll
      for (int nt = 0; nt < 4; ++nt) {
        const int dk = nt * 16 + i16;
        const int slot = ((mt << 1) | (q4 >> 1)) ^ (dk & 7);
        bf16x4 vb = *(const bf16x4*)(Vtu + dk * 64 + (slot << 3) + ((q4 & 1) << 2));
        o_acc[nt] = mfma16x16x16(pf[u][mt], vb, o_acc[nt]);
      }
    }
  }
  SETPRIO(0);
}

// ---------------------------------------------------------------------------
// Kernel 2: MFMA causal flash attention, S^T, 128-key pairs, TWO q-tiles
// per block + T5 setprio + T14 async-STAGE split: tile pr+1's K/V global
// loads issue into registers right after the commit barrier (HBM latency
// hides under the two attn_steps); registers commit to LDS after the next
// barrier. Prefetch = 6x uint4 = 24 VGPR on a 92-VGPR base -> ~116, under
// the 128 cliff (round-4's failure was 128+24 -> spill).
// grid = (SEQ/128, B*H).
// ---------------------------------------------------------------------------
__global__ __launch_bounds__(256) void attn_mfma_kernel(
    const unsigned short* __restrict__ Q, const unsigned short* __restrict__ K,
    const unsigned short* __restrict__ V, unsigned short* __restrict__ O) {
  __shared__ __align__(16) unsigned short Ks[2][64 * 64];
  __shared__ __align__(16) unsigned short Vt[2][64 * 64];

  const int t = threadIdx.x, w = t >> 6, lane = t & 63;
  const int i16 = lane & 15, q4 = lane >> 4;
  const int bh = blockIdx.y;
  const int qbA = blockIdx.x;              // short tile: 0..15
  const int qbB = 31 - blockIdx.x;         // long tile: 16..31
  const int q0A = qbA * 64, q0B = qbB * 64;
  const size_t base = (size_t)bh * SEQ * DK;

  bf16x8 qfA0, qfA1, qfB0, qfB1;
  {
    const unsigned short* qpA = Q + base + (size_t)(q0A + w * 16 + i16) * DK + q4 * 8;
    qfA0 = *(const bf16x8*)(qpA);
    qfA1 = *(const bf16x8*)(qpA + 32);
    const unsigned short* qpB = Q + base + (size_t)(q0B + w * 16 + i16) * DK + q4 * 8;
    qfB0 = *(const bf16x8*)(qpB);
    qfB1 = *(const bf16x8*)(qpB + 32);
  }

  f32x4 oA[4], oB[4];
#pragma unroll
  for (int n = 0; n < 4; ++n) {
    oA[n] = (f32x4){0.f, 0.f, 0.f, 0.f};
    oB[n] = (f32x4){0.f, 0.f, 0.f, 0.f};
  }
  float mA = NEG_BIG, lA = 0.f, mB = NEG_BIG, lB = 0.f;

  const int krow = t >> 2;
  const int kc   = (t & 3) << 1;
  const int kr7  = krow & 7;
  const int vu   = t >> 7;            // which half this thread stages for V
  const int tl   = t & 127;
  const int vkq  = (tl & 15) << 2;
  const int vd8  = (tl >> 4) << 3;
  const int vg   = vkq >> 3;
  const int vh   = (vkq >> 2) & 1;

  const int npairA = (qbA >> 1) + 1;
  const int npairB = (qbB >> 1) + 1;

  const unsigned short* kbase = K + base + (size_t)krow * DK + (kc << 3);
  const unsigned short* vbase = V + base + (size_t)(vu * 64 + vkq) * DK + vd8;

  uint4 kreg[2][2];
  uint4 vreg[4];

  // ---- prefetch tile 0 into registers ----
#pragma unroll
  for (int u = 0; u < 2; ++u) {
    const unsigned short* kp = kbase + (size_t)(u * 64) * DK;
    kreg[u][0] = *(const uint4*)kp;
    kreg[u][1] = *(const uint4*)(kp + 8);
  }
  {
    vreg[0] = *(const uint4*)(vbase);
    vreg[1] = *(const uint4*)(vbase + DK);
    vreg[2] = *(const uint4*)(vbase + 2 * DK);
    vreg[3] = *(const uint4*)(vbase + 3 * DK);
  }

  for (int pr = 0; pr < npairB; ++pr) {
    const int kt2 = pr * 2;
    __syncthreads();
    // ---- commit registers -> LDS (K swizzled, V transposed+swizzled) ----
#pragma unroll
    for (int u = 0; u < 2; ++u) {
      *(uint4*)(Ks[u] + krow * 64 + ((kc ^ kr7) << 3))       = kreg[u][0];
      *(uint4*)(Ks[u] + krow * 64 + (((kc + 1) ^ kr7) << 3)) = kreg[u][1];
    }
    {
      const unsigned short* a0 = (const unsigned short*)&vreg[0];
      const unsigned short* a1 = (const unsigned short*)&vreg[1];
      const unsigned short* a2 = (const unsigned short*)&vreg[2];
      const unsigned short* a3 = (const unsigned short*)&vreg[3];
#pragma unroll
      for (int j = 0; j < 8; ++j) {
        const int dk = vd8 + j;
        const int slot = vg ^ (dk & 7);
        ushort4 pk;
        pk.x = a0[j]; pk.y = a1[j]; pk.z = a2[j]; pk.w = a3[j];
        *(ushort4*)(Vt[vu] + dk * 64 + (slot << 3) + (vh << 2)) = pk;
      }
    }
    __syncthreads();

    // ---- issue next tile's global loads (T14: hide under attn_steps) ----
    if (pr + 1 < npairB) {
      const size_t off = (size_t)((pr + 1) * 128) * DK;
#pragma unroll
      for (int u = 0; u < 2; ++u) {
        const unsigned short* kp = kbase + off + (size_t)(u * 64) * DK;
        kreg[u][0] = *(const uint4*)kp;
        kreg[u][1] = *(const uint4*)(kp + 8);
      }
      const unsigned short* vp = vbase + off;
      vreg[0] = *(const uint4*)(vp);
      vreg[1] = *(const uint4*)(vp + DK);
      vreg[2] = *(const uint4*)(vp + 2 * DK);
      vreg[3] = *(const uint4*)(vp + 3 * DK);
    }

    // ---- long tile always; short tile while in range (uniform branches) ----
    attn_step(Ks[0], Ks[1], Vt[0], Vt[1], qfB0, qfB1, i16, q4, w,
              q0B, kt2, pr == npairB - 1, mB, lB, oB);
    if (pr < npairA)
      attn_step(Ks[0], Ks[1], Vt[0], Vt[1], qfA0, qfA1, i16, q4, w,
                q0A, kt2, pr == npairA - 1, mA, lA, oA);
  }

  // ---- epilogues ----
  const int b = bh >> 4, h = bh & 15;
#pragma unroll
  for (int r = 0; r < 4; ++r) {
    const float lrA = __shfl(lA, (q4 << 2) + r, 64);
    const float lrB = __shfl(lB, (q4 << 2) + r, 64);
    const float invA = 1.0f / lrA;
    const float invB = 1.0f / lrB;
    const int sA = q0A + w * 16 + (q4 << 2) + r;
    const int sB = q0B + w * 16 + (q4 << 2) + r;
#pragma unroll
    for (int nt = 0; nt < 4; ++nt) {
      const int dk = nt * 16 + i16;
      O[((size_t)(b * SEQ + sA)) * D_MODEL + h * DK + dk] = f2bf(oA[nt][r] * invA);
      O[((size_t)(b * SEQ + sB)) * D_MODEL + h * DK + dk] = f2bf(oB[nt][r] * invB);
    }
  }
}

// ---------------------------------------------------------------------------
// Kernel 3: output projection -> fp32, float4 packed stores. grid (32, 16).
// NF=2; XCD-aware swizzle (same scheme as qkv, 512 blocks, 512%8==0).
// ---------------------------------------------------------------------------
__global__ __launch_bounds__(256) void oproj_kernel(
    const unsigned short* __restrict__ ain, const unsigned short* __restrict__ wo,
    float* __restrict__ out) {
  __shared__ __align__(16) unsigned short As[128 * 64];
  __shared__ __align__(16) unsigned short Bs[64 * 64];
  f32x4 acc[2][4];
  const int lin = blockIdx.y * 32 + blockIdx.x;   // 0..511
  const int c8  = lin & 7;
  const int i   = lin >> 3;                       // 0..63
  const int m0  = (c8 * 4 + (i & 3)) * 128;
  const int n0  = (i >> 2) * 64;
  gemm_bt_t<2>(ain, wo, m0, n0, As, Bs, acc);

  const int t = threadIdx.x, lane = t & 63, w = t >> 6;
  const int wm = (w >> 1) * 64, wn = (w & 1) * 32;
  const int i16 = lane & 15, q4 = lane >> 4;
#pragma unroll
  for (int ft = 0; ft < 2; ++ft) {
    const int nb0 = n0 + wn + ft * 16 + (q4 << 2);
#pragma unroll
    for (int tt = 0; tt < 4; ++tt) {
      const int m = m0 + wm + tt * 16 + i16;
      float4 v;
      v.x = acc[ft][tt][0]; v.y = acc[ft][tt][1];
      v.z = acc[ft][tt][2]; v.w = acc[ft][tt][3];
      *(float4*)(out + (size_t)m * D_MODEL + nb0) = v;
    }
  }
}

// ---------------------------------------------------------------------------
extern "C" void kernel_launch(void* const* d_in, const int* in_sizes, int n_in,
                              void* d_out, int out_size, void* d_ws, size_t ws_size,
                              hipStream_t stream) {
  const void* x    = d_in[0];
  const void* wqkv = d_in[2];
  const void* wo   = d_in[3];
  float* out = (float*)d_out;

  const size_t NTOK  = (size_t)NBATCH * SEQ * D_MODEL;  // 4,194,304 elements
  const size_t NWQKV = (size_t)3 * D_MODEL * D_MODEL;   // 3,145,728
  const size_t NWO   = (size_t)D_MODEL * D_MODEL;       // 1,048,576

  unsigned short* base = (unsigned short*)((char*)d_ws + 16);
  unsigned short* Qw = base;                 // NTOK
  unsigned short* Kw = Qw + NTOK;            // NTOK
  unsigned short* Vw = Kw + NTOK;            // NTOK
  unsigned short* Aw = Vw + NTOK;            // NTOK (aliases xb; xb dead before attn writes)
  unsigned short* xb = Aw;                   // canonical bf16 x
  unsigned short* wq = Aw + NTOK;            // NWQKV

  dim3 blk(256);

  // Workspace for a SEPARATE wb (no aliasing) needs:
  const size_t need = 16 + (4 * NTOK + NWQKV + NWO) * sizeof(unsigned short);

  if (ws_size >= need) {
    // Single canonicalization dispatch: x + wqkv + wo.
    // blocks: 2048 + 1536 + 512 = 4096.
    unsigned short* wb = wq + NWQKV;
    hipLaunchKernelGGL(cvt3_kernel, dim3(4096), blk, 0, stream,
                       x, xb, (int)(NTOK / 8), wqkv, wq, (int)(NWQKV / 8),
                       wo, wb);

    dim3 g1(32, 24);
    hipLaunchKernelGGL(qkv_rope_kernel, g1, blk, 0, stream, xb, wq, Qw, Kw, Vw);

    dim3 g2(SEQ / 128, NBATCH * NHEADS);
    hipLaunchKernelGGL(attn_mfma_kernel, g2, blk, 0, stream, Qw, Kw, Vw, Aw);

    dim3 g3(32, 16);
    hipLaunchKernelGGL(oproj_kernel, g3, blk, 0, stream, Aw, wb, out);
  } else {
    // Fallback (round-5 proven path): wb aliases wq, converted after qkv.
    unsigned short* wb = wq;
    hipLaunchKernelGGL(cvt2_kernel, dim3(3584), blk, 0, stream,
                       x, xb, (int)(NTOK / 8), wqkv, wq, (int)(NWQKV / 8));

    dim3 g1(32, 24);
    hipLaunchKernelGGL(qkv_rope_kernel, g1, blk, 0, stream, xb, wq, Qw, Kw, Vw);

    dim3 g2(SEQ / 128, NBATCH * NHEADS);
    hipLaunchKernelGGL(attn_mfma_kernel, g2, blk, 0, stream, Qw, Kw, Vw, Aw);

    hipLaunchKernelGGL(cvt2_kernel, dim3(512), blk, 0, stream,
                       wo, wb, (int)(NWO / 8), wo, wb, 0);

    dim3 g3(32, 16);
    hipLaunchKernelGGL(oproj_kernel, g3, blk, 0, stream, Aw, wb, out);
  }
}

// Round 8
// 191.658 us; speedup vs baseline: 1.1544x; 1.1544x over previous
//
#include <hip/hip_runtime.h>
#include <cstdint>
#include <cstddef>

#define D_MODEL 1024
#define NHEADS  16
#define DK      64
#define SEQ     2048
#define NBATCH  2

#define NEG_BIG (-1e30f)

typedef __attribute__((ext_vector_type(8))) short bf16x8;
typedef __attribute__((ext_vector_type(4))) short bf16x4;
typedef __attribute__((ext_vector_type(4))) float f32x4;

#if defined(__AMDGCN__)
#define SETPRIO(p) __builtin_amdgcn_s_setprio(p)
#else
#define SETPRIO(p)
#endif

// Host pass: amdgcn builtins unavailable -> guard on __AMDGCN__.
__device__ inline f32x4 mfma16x16x16(bf16x4 a, bf16x4 b, f32x4 c) {
#if defined(__AMDGCN__)
# if __has_builtin(__builtin_amdgcn_mfma_f32_16x16x16_bf16)
  return __builtin_amdgcn_mfma_f32_16x16x16_bf16(a, b, c, 0, 0, 0);
# else
  return __builtin_amdgcn_mfma_f32_16x16x16bf16_1k(a, b, c, 0, 0, 0);
# endif
#else
  (void)a; (void)b;
  return c;
#endif
}

__device__ inline void gll16(const unsigned short* g, unsigned short* l) {
#if defined(__AMDGCN__)
  __builtin_amdgcn_global_load_lds(
      (const __attribute__((address_space(1))) void*)g,
      (__attribute__((address_space(3))) void*)l, 16, 0, 0);
#else
  (void)g; (void)l;
#endif
}

__device__ inline unsigned short f2bf(float f) {
  unsigned int u = __float_as_uint(f);
  u += 0x7fffu + ((u >> 16) & 1u);   // round-to-nearest-even
  return (unsigned short)(u >> 16);
}

// ---------------------------------------------------------------------------
// Per-block dtype sniff + convert-8-elements helper (shared by cvt2/cvt3).
// fp32 data: even-index shorts are mantissa noise -> ~48% hit e-field>=0x84;
// bf16 N(0,1)-scale data: ~0%. Threshold 64/1024 per block.
// ---------------------------------------------------------------------------
__device__ __forceinline__ void cvt_block(const void* src,
                                          unsigned short* dst, int i0) {
  const unsigned short* sp =
      (const unsigned short*)src + (size_t)i0 * 8 + threadIdx.x * 8;
  int cnt = 0;
#pragma unroll
  for (int j = 0; j < 8; j += 2) {
    const unsigned int u = sp[j];
    cnt += (((u >> 7) & 0xFFu) >= 0x84u) ? 1 : 0;
  }
  __shared__ int red[256];
  red[threadIdx.x] = cnt;
  __syncthreads();
  for (int s = 128; s > 0; s >>= 1) {
    if (threadIdx.x < s) red[threadIdx.x] += red[threadIdx.x + s];
    __syncthreads();
  }
  const bool isf32 = red[0] > 64;

  const int i = i0 + threadIdx.x;
  if (isf32) {
    const float4* s = (const float4*)src;
    float4 a = s[2 * i], b = s[2 * i + 1];
    uint4 r;
    r.x = (unsigned)f2bf(a.x) | ((unsigned)f2bf(a.y) << 16);
    r.y = (unsigned)f2bf(a.z) | ((unsigned)f2bf(a.w) << 16);
    r.z = (unsigned)f2bf(b.x) | ((unsigned)f2bf(b.y) << 16);
    r.w = (unsigned)f2bf(b.z) | ((unsigned)f2bf(b.w) << 16);
    ((uint4*)dst)[i] = r;
  } else {
    ((uint4*)dst)[i] = ((const uint4*)src)[i];
  }
}

// Two-buffer canonicalize (fallback path when workspace is tight).
__global__ __launch_bounds__(256) void cvt2_kernel(
    const void* __restrict__ srcA, unsigned short* __restrict__ dstA, int n8A,
    const void* __restrict__ srcB, unsigned short* __restrict__ dstB, int n8B) {
  const int bi = blockIdx.x;
  const int nblkA = n8A >> 8;
  (void)n8B;
  if (bi < nblkA) cvt_block(srcA, dstA, bi << 8);
  else            cvt_block(srcB, dstB, (bi - nblkA) << 8);
}

// Three-buffer canonicalize: x + wqkv + wo in ONE dispatch.
__global__ __launch_bounds__(256) void cvt3_kernel(
    const void* __restrict__ srcA, unsigned short* __restrict__ dstA, int n8A,
    const void* __restrict__ srcB, unsigned short* __restrict__ dstB, int n8B,
    const void* __restrict__ srcC, unsigned short* __restrict__ dstC) {
  const int bi = blockIdx.x;
  const int nblkA = n8A >> 8;
  const int nblkB = n8B >> 8;
  if (bi < nblkA)               cvt_block(srcA, dstA, bi << 8);
  else if (bi < nblkA + nblkB)  cvt_block(srcB, dstB, (bi - nblkA) << 8);
  else                          cvt_block(srcC, dstC, (bi - nblkA - nblkB) << 8);
}

// ---------------------------------------------------------------------------
// 128 x (NF*32) tile GEMM mainloop, transposed-C, BK=64, async staging with
// SOURCE-PERMUTED global_load_lds: lane fetches granule (t&7)^(row&7) so
// the fixed dest layout lands XOR-swizzled -> conflict-free b128 frag reads.
// LDS rows of 128B: As[128][64], Bs[NF*32][64] (bf16). 16 K-iterations.
// ---------------------------------------------------------------------------
template <int NF>
__device__ inline void gemm_bt_t(const unsigned short* __restrict__ A,
                                 const unsigned short* __restrict__ W,
                                 int m0, int n0,
                                 unsigned short* As, unsigned short* Bs,
                                 f32x4 (&acc)[NF][4]) {
  const int t    = threadIdx.x;
  const int lane = t & 63;
  const int w    = t >> 6;
  const int wm   = (w >> 1) * 64;        // token offset
  const int wn   = (w & 1) * (NF * 16);  // feature offset
  const int frow = lane & 15;
  const int q4   = lane >> 4;            // granule base (0..3)

  for (int ft = 0; ft < NF; ++ft)
    for (int tt = 0; tt < 4; ++tt)
      acc[ft][tt] = (f32x4){0.f, 0.f, 0.f, 0.f};

  const int srow  = t >> 3;         // 0..31 (row within 32-row chunk)
  const int gslot = t & 7;          // dest granule slot

  for (int k0 = 0; k0 < 1024; k0 += 64) {
    __syncthreads();
#pragma unroll
    for (int c = 0; c < 4; ++c) {   // A: 4 chunks x 32 rows
      const int row = c * 32 + srow;
      const int gsrc = gslot ^ (row & 7);
      gll16(A + (size_t)(m0 + row) * 1024 + k0 + gsrc * 8,
            As + ((size_t)t + 256 * c) * 8);
    }
#pragma unroll
    for (int c = 0; c < NF; ++c) {  // B: NF chunks x 32 rows
      const int row = c * 32 + srow;
      const int gsrc = gslot ^ (row & 7);
      gll16(W + (size_t)(n0 + row) * 1024 + k0 + gsrc * 8,
            Bs + ((size_t)t + 256 * c) * 8);
    }
    __syncthreads();

#pragma unroll
    for (int kk = 0; kk < 2; ++kk) {
      const int gg = q4 + kk * 4;   // wanted global granule
      bf16x8 xv[4], wv[NF];
#pragma unroll
      for (int tt = 0; tt < 4; ++tt) {
        const int row = wm + tt * 16 + frow;
        xv[tt] = *(const bf16x8*)(As + row * 64 + ((gg ^ (row & 7)) << 3));
      }
#pragma unroll
      for (int ft = 0; ft < NF; ++ft) {
        const int row = wn + ft * 16 + frow;
        wv[ft] = *(const bf16x8*)(Bs + row * 64 + ((gg ^ (row & 7)) << 3));
      }
#pragma unroll
      for (int ft = 0; ft < NF; ++ft)
#pragma unroll
        for (int tt = 0; tt < 4; ++tt)
          acc[ft][tt] = __builtin_amdgcn_mfma_f32_16x16x32_bf16(wv[ft], xv[tt],
                                                                acc[ft][tt], 0, 0, 0);
    }
  }
}

// ---------------------------------------------------------------------------
// Kernel 1: QKV projection + fused RoPE. 128x128 tile (NF=4), grid 768.
// XCD-aware swizzle (T1). V is written TRANSPOSED to global ([bh][d][s])
// so attention can stage it with source-permuted global_load_lds (no
// in-kernel transpose, no staging registers).
// ---------------------------------------------------------------------------
__global__ __launch_bounds__(256) void qkv_rope_kernel(
    const unsigned short* __restrict__ x,
    const unsigned short* __restrict__ wqkv,
    unsigned short* __restrict__ Qw, unsigned short* __restrict__ Kw,
    unsigned short* __restrict__ Vw) {
  __shared__ __align__(16) unsigned short As[128 * 64];
  __shared__ __align__(16) unsigned short Bs[128 * 64];
  f32x4 acc[4][4];
  const int lin = blockIdx.y * 32 + blockIdx.x;   // 0..767
  const int c8  = lin & 7;                        // XCD (round-robin)
  const int i   = lin >> 3;                       // 0..95
  const int m0  = (c8 * 4 + (i & 3)) * 128;       // bijective remap
  const int n0  = (i >> 2) * 128;
  gemm_bt_t<4>(x, wqkv, m0, n0, As, Bs, acc);

  const int t = threadIdx.x, lane = t & 63, w = t >> 6;
  const int wm = (w >> 1) * 64, wn = (w & 1) * 64;
  const int i16 = lane & 15, q4 = lane >> 4;
  const int part = n0 >> 10;               // block-uniform
  const float LN_THETA_OVER_HALF = 0.2878231366242558f;  // ln(10000)/32

#pragma unroll
  for (int ft = 0; ft < 4; ++ft) {
    const int nb0 = n0 + wn + ft * 16 + (q4 << 2);  // 4 consecutive features
    const int h  = (nb0 >> 6) & 15;
    const int d0 = nb0 & 63;
    const float invf0 = __expf(-(float)(d0 >> 1) * LN_THETA_OVER_HALF);
    const float invf1 = __expf(-(float)((d0 >> 1) + 1) * LN_THETA_OVER_HALF);
#pragma unroll
    for (int tt = 0; tt < 4; ++tt) {
      const int m = m0 + wm + tt * 16 + i16;
      const int b = m >> 11, s = m & 2047;
      float v0 = acc[ft][tt][0], v1 = acc[ft][tt][1];
      float v2 = acc[ft][tt][2], v3 = acc[ft][tt][3];
      if (part < 2) {
        float sn0, cs0, sn1, cs1;
        __sincosf((float)s * invf0, &sn0, &cs0);
        __sincosf((float)s * invf1, &sn1, &cs1);
        const float r0 = v0 * cs0 - v1 * sn0;
        const float r1 = v0 * sn0 + v1 * cs0;
        const float r2 = v2 * cs1 - v3 * sn1;
        const float r3 = v2 * sn1 + v3 * cs1;
        v0 = r0; v1 = r1; v2 = r2; v3 = r3;
        if (part == 0) { v0 *= 0.125f; v1 *= 0.125f; v2 *= 0.125f; v3 *= 0.125f; }
        ushort4 pk;
        pk.x = f2bf(v0); pk.y = f2bf(v1); pk.z = f2bf(v2); pk.w = f2bf(v3);
        unsigned short* dst = (part == 0) ? Qw : Kw;
        *(ushort4*)(dst + (((size_t)(b * NHEADS + h)) * SEQ + s) * DK + d0) = pk;
      } else {
        // V^T: [bh][d][s]. 4 scalar stores (4x32B segments per wave store).
        unsigned short* vt =
            Vw + (((size_t)(b * NHEADS + h)) * DK + d0) * SEQ + s;
        vt[0]       = f2bf(v0);
        vt[SEQ]     = f2bf(v1);
        vt[2 * SEQ] = f2bf(v2);
        vt[3 * SEQ] = f2bf(v3);
      }
    }
  }
}

// ---------------------------------------------------------------------------
// Per-128-key attention step for one q-tile (S^T formulation, R8-verified).
// T5 setprio around MFMA clusters (also cut VGPR 128->92 in R6).
// ---------------------------------------------------------------------------
__device__ __forceinline__ void attn_step(
    const unsigned short* Ks0, const unsigned short* Ks1,
    const unsigned short* Vt0, const unsigned short* Vt1,
    bf16x8 qf0, bf16x8 qf1, int i16, int q4, int w,
    int q0t, int kt2, bool domask,
    float& m_i, float& l_i, f32x4 o_acc[4]) {
  // ---- S^T for both halves ----
  f32x4 s_acc[2][4];
  SETPRIO(1);
#pragma unroll
  for (int u = 0; u < 2; ++u) {
    const unsigned short* Ksu = u ? Ks1 : Ks0;
#pragma unroll
    for (int mt = 0; mt < 4; ++mt) {
      const int key = mt * 16 + i16;
      const int k7 = key & 7;
      bf16x8 a0 = *(const bf16x8*)(Ksu + key * 64 + ((q4 ^ k7) << 3));
      bf16x8 a1 = *(const bf16x8*)(Ksu + key * 64 + (((4 + q4) ^ k7) << 3));
      f32x4 acc = (f32x4){0.f, 0.f, 0.f, 0.f};
      acc = __builtin_amdgcn_mfma_f32_16x16x32_bf16(a0, qf0, acc, 0, 0, 0);
      acc = __builtin_amdgcn_mfma_f32_16x16x32_bf16(a1, qf1, acc, 0, 0, 0);
      s_acc[u][mt] = acc;
    }
  }
  SETPRIO(0);

  // ---- causal mask on final pair of this tile (block-uniform branch) ----
  if (domask) {
    const int qrow = q0t + w * 16 + i16;
#pragma unroll
    for (int u = 0; u < 2; ++u) {
      const int kb2 = (kt2 + u) * 64 + q4 * 4;
#pragma unroll
      for (int mt = 0; mt < 4; ++mt)
#pragma unroll
        for (int r = 0; r < 4; ++r)
          if (kb2 + mt * 16 + r > qrow) s_acc[u][mt][r] = NEG_BIG;
    }
  }

  // ---- online softmax over 128 keys ----
  float tm = NEG_BIG;
#pragma unroll
  for (int u = 0; u < 2; ++u)
#pragma unroll
    for (int mt = 0; mt < 4; ++mt)
#pragma unroll
      for (int r = 0; r < 4; ++r) tm = fmaxf(tm, s_acc[u][mt][r]);
  tm = fmaxf(tm, __shfl_xor(tm, 16, 64));
  tm = fmaxf(tm, __shfl_xor(tm, 32, 64));
  const float m_new = fmaxf(m_i, tm);
  const float alpha = __expf(m_i - m_new);
  m_i = m_new;

  bf16x4 pf[2][4];
  float ls = 0.f;
#pragma unroll
  for (int u = 0; u < 2; ++u)
#pragma unroll
    for (int mt = 0; mt < 4; ++mt) {
      float p0 = __expf(s_acc[u][mt][0] - m_new);
      float p1 = __expf(s_acc[u][mt][1] - m_new);
      float p2 = __expf(s_acc[u][mt][2] - m_new);
      float p3 = __expf(s_acc[u][mt][3] - m_new);
      ls += (p0 + p1) + (p2 + p3);
      pf[u][mt][0] = (short)f2bf(p0);
      pf[u][mt][1] = (short)f2bf(p1);
      pf[u][mt][2] = (short)f2bf(p2);
      pf[u][mt][3] = (short)f2bf(p3);
    }
  ls += __shfl_xor(ls, 16, 64);
  ls += __shfl_xor(ls, 32, 64);
  l_i = l_i * alpha + ls;

  float a4[4];
#pragma unroll
  for (int r = 0; r < 4; ++r) a4[r] = __shfl(alpha, (q4 << 2) + r, 64);
#pragma unroll
  for (int n = 0; n < 4; ++n)
#pragma unroll
    for (int r = 0; r < 4; ++r) o_acc[n][r] *= a4[r];

  // ---- PV over both halves ----
  SETPRIO(1);
#pragma unroll
  for (int u = 0; u < 2; ++u) {
    const unsigned short* Vtu = u ? Vt1 : Vt0;
#pragma unroll
    for (int mt = 0; mt < 4; ++mt) {
#pragma unroll
      for (int nt = 0; nt < 4; ++nt) {
        const int dk = nt * 16 + i16;
        const int slot = ((mt << 1) | (q4 >> 1)) ^ (dk & 7);
        bf16x4 vb = *(const bf16x4*)(Vtu + dk * 64 + (slot << 3) + ((q4 & 1) << 2));
        o_acc[nt] = mfma16x16x16(pf[u][mt], vb, o_acc[nt]);
      }
    }
  }
  SETPRIO(0);
}

// ---------------------------------------------------------------------------
// Kernel 2: MFMA causal flash attention, S^T, 128-key pairs, TWO q-tiles
// per block + T5 setprio + DOUBLE-BUFFERED register-free staging:
// K (row-major) and V^T (d-major) both staged via source-permuted
// global_load_lds (m97 GEMM pattern) -> zero staging VGPRs (nothing to
// spill; R4/R7's T14-by-register failures are structurally impossible).
// Tile pr+1's 8 gll16 issue right after the barrier; compute on tile pr
// runs while they fly; the compiler's vmcnt(0) drain at the NEXT barrier
// lands after ~1500cy of MFMA+VALU. LDS 64 KB -> still 2 blocks/CU.
// grid = (SEQ/128, B*H).
// ---------------------------------------------------------------------------
__global__ __launch_bounds__(256) void attn_mfma_kernel(
    const unsigned short* __restrict__ Q, const unsigned short* __restrict__ K,
    const unsigned short* __restrict__ VT, unsigned short* __restrict__ O) {
  __shared__ __align__(16) unsigned short Ks[2][2][64 * 64];  // [buf][half]
  __shared__ __align__(16) unsigned short Vt[2][2][64 * 64];  // [buf][half]

  const int t = threadIdx.x, w = t >> 6, lane = t & 63;
  const int i16 = lane & 15, q4 = lane >> 4;
  const int bh = blockIdx.y;
  const int qbA = blockIdx.x;              // short tile: 0..15
  const int qbB = 31 - blockIdx.x;         // long tile: 16..31
  const int q0A = qbA * 64, q0B = qbB * 64;
  const size_t base = (size_t)bh * SEQ * DK;

  const int srow  = t >> 3;   // 0..31
  const int gslot = t & 7;

  // stage pair p into buffer buf: 128 K-rows + 128 V^T-rows, granule-swizzled
  // on the SOURCE so the linear LDS dest lands XOR-swizzled (read layout
  // identical to the previous ds_write staging).
  auto stage = [&](int p, int buf) {
#pragma unroll
    for (int c = 0; c < 4; ++c) {
      const int row = srow + 32 * c;          // 0..127 (half u = row>>6)
      const int gs  = gslot ^ (row & 7);
      gll16(K + base + (size_t)(p * 128 + row) * DK + gs * 8,
            &Ks[buf][0][0] + ((size_t)t + 256 * c) * 8);
    }
#pragma unroll
    for (int c = 0; c < 4; ++c) {
      const int row = srow + 32 * c;          // u = row>>6, dk = row&63
      const int gs  = gslot ^ (row & 7);      // dk&7 == row&7
      gll16(VT + base + (size_t)(row & 63) * SEQ
               + p * 128 + (row >> 6) * 64 + gs * 8,
            &Vt[buf][0][0] + ((size_t)t + 256 * c) * 8);
    }
  };

  bf16x8 qfA0, qfA1, qfB0, qfB1;
  {
    const unsigned short* qpA = Q + base + (size_t)(q0A + w * 16 + i16) * DK + q4 * 8;
    qfA0 = *(const bf16x8*)(qpA);
    qfA1 = *(const bf16x8*)(qpA + 32);
    const unsigned short* qpB = Q + base + (size_t)(q0B + w * 16 + i16) * DK + q4 * 8;
    qfB0 = *(const bf16x8*)(qpB);
    qfB1 = *(const bf16x8*)(qpB + 32);
  }

  f32x4 oA[4], oB[4];
#pragma unroll
  for (int n = 0; n < 4; ++n) {
    oA[n] = (f32x4){0.f, 0.f, 0.f, 0.f};
    oB[n] = (f32x4){0.f, 0.f, 0.f, 0.f};
  }
  float mA = NEG_BIG, lA = 0.f, mB = NEG_BIG, lB = 0.f;

  const int npairA = (qbA >> 1) + 1;
  const int npairB = (qbB >> 1) + 1;

  stage(0, 0);                               // prologue

  for (int pr = 0; pr < npairB; ++pr) {
    const int kt2 = pr * 2;
    const int cb = pr & 1;
    __syncthreads();                         // drains stage(pr) -> buf cb ready
    if (pr + 1 < npairB) stage(pr + 1, cb ^ 1);   // async; hides under compute

    attn_step(Ks[cb][0], Ks[cb][1], Vt[cb][0], Vt[cb][1], qfB0, qfB1,
              i16, q4, w, q0B, kt2, pr == npairB - 1, mB, lB, oB);
    if (pr < npairA)
      attn_step(Ks[cb][0], Ks[cb][1], Vt[cb][0], Vt[cb][1], qfA0, qfA1,
                i16, q4, w, q0A, kt2, pr == npairA - 1, mA, lA, oA);
  }

  // ---- epilogues ----
  const int b = bh >> 4, h = bh & 15;
#pragma unroll
  for (int r = 0; r < 4; ++r) {
    const float lrA = __shfl(lA, (q4 << 2) + r, 64);
    const float lrB = __shfl(lB, (q4 << 2) + r, 64);
    const float invA = 1.0f / lrA;
    const float invB = 1.0f / lrB;
    const int sA = q0A + w * 16 + (q4 << 2) + r;
    const int sB = q0B + w * 16 + (q4 << 2) + r;
#pragma unroll
    for (int nt = 0; nt < 4; ++nt) {
      const int dk = nt * 16 + i16;
      O[((size_t)(b * SEQ + sA)) * D_MODEL + h * DK + dk] = f2bf(oA[nt][r] * invA);
      O[((size_t)(b * SEQ + sB)) * D_MODEL + h * DK + dk] = f2bf(oB[nt][r] * invB);
    }
  }
}

// ---------------------------------------------------------------------------
// Kernel 3: output projection -> fp32, float4 packed stores. grid (32, 16).
// NF=2; XCD-aware swizzle (same scheme as qkv, 512 blocks, 512%8==0).
// ---------------------------------------------------------------------------
__global__ __launch_bounds__(256) void oproj_kernel(
    const unsigned short* __restrict__ ain, const unsigned short* __restrict__ wo,
    float* __restrict__ out) {
  __shared__ __align__(16) unsigned short As[128 * 64];
  __shared__ __align__(16) unsigned short Bs[64 * 64];
  f32x4 acc[2][4];
  const int lin = blockIdx.y * 32 + blockIdx.x;   // 0..511
  const int c8  = lin & 7;
  const int i   = lin >> 3;                       // 0..63
  const int m0  = (c8 * 4 + (i & 3)) * 128;
  const int n0  = (i >> 2) * 64;
  gemm_bt_t<2>(ain, wo, m0, n0, As, Bs, acc);

  const int t = threadIdx.x, lane = t & 63, w = t >> 6;
  const int wm = (w >> 1) * 64, wn = (w & 1) * 32;
  const int i16 = lane & 15, q4 = lane >> 4;
#pragma unroll
  for (int ft = 0; ft < 2; ++ft) {
    const int nb0 = n0 + wn + ft * 16 + (q4 << 2);
#pragma unroll
    for (int tt = 0; tt < 4; ++tt) {
      const int m = m0 + wm + tt * 16 + i16;
      float4 v;
      v.x = acc[ft][tt][0]; v.y = acc[ft][tt][1];
      v.z = acc[ft][tt][2]; v.w = acc[ft][tt][3];
      *(float4*)(out + (size_t)m * D_MODEL + nb0) = v;
    }
  }
}

// ---------------------------------------------------------------------------
extern "C" void kernel_launch(void* const* d_in, const int* in_sizes, int n_in,
                              void* d_out, int out_size, void* d_ws, size_t ws_size,
                              hipStream_t stream) {
  const void* x    = d_in[0];
  const void* wqkv = d_in[2];
  const void* wo   = d_in[3];
  float* out = (float*)d_out;

  const size_t NTOK  = (size_t)NBATCH * SEQ * D_MODEL;  // 4,194,304 elements
  const size_t NWQKV = (size_t)3 * D_MODEL * D_MODEL;   // 3,145,728
  const size_t NWO   = (size_t)D_MODEL * D_MODEL;       // 1,048,576

  unsigned short* base = (unsigned short*)((char*)d_ws + 16);
  unsigned short* Qw = base;                 // NTOK
  unsigned short* Kw = Qw + NTOK;            // NTOK
  unsigned short* Vw = Kw + NTOK;            // NTOK (V^T layout [bh][d][s])
  unsigned short* Aw = Vw + NTOK;            // NTOK (aliases xb; xb dead before attn writes)
  unsigned short* xb = Aw;                   // canonical bf16 x
  unsigned short* wq = Aw + NTOK;            // NWQKV

  dim3 blk(256);

  // Workspace for a SEPARATE wb (no aliasing) needs:
  const size_t need = 16 + (4 * NTOK + NWQKV + NWO) * sizeof(unsigned short);

  if (ws_size >= need) {
    // Single canonicalization dispatch: x + wqkv + wo.
    unsigned short* wb = wq + NWQKV;
    hipLaunchKernelGGL(cvt3_kernel, dim3(4096), blk, 0, stream,
                       x, xb, (int)(NTOK / 8), wqkv, wq, (int)(NWQKV / 8),
                       wo, wb);

    dim3 g1(32, 24);
    hipLaunchKernelGGL(qkv_rope_kernel, g1, blk, 0, stream, xb, wq, Qw, Kw, Vw);

    dim3 g2(SEQ / 128, NBATCH * NHEADS);
    hipLaunchKernelGGL(attn_mfma_kernel, g2, blk, 0, stream, Qw, Kw, Vw, Aw);

    dim3 g3(32, 16);
    hipLaunchKernelGGL(oproj_kernel, g3, blk, 0, stream, Aw, wb, out);
  } else {
    // Fallback: wb aliases wq, converted after qkv.
    unsigned short* wb = wq;
    hipLaunchKernelGGL(cvt2_kernel, dim3(3584), blk, 0, stream,
                       x, xb, (int)(NTOK / 8), wqkv, wq, (int)(NWQKV / 8));

    dim3 g1(32, 24);
    hipLaunchKernelGGL(qkv_rope_kernel, g1, blk, 0, stream, xb, wq, Qw, Kw, Vw);

    dim3 g2(SEQ / 128, NBATCH * NHEADS);
    hipLaunchKernelGGL(attn_mfma_kernel, g2, blk, 0, stream, Qw, Kw, Vw, Aw);

    hipLaunchKernelGGL(cvt2_kernel, dim3(512), blk, 0, stream,
                       wo, wb, (int)(NWO / 8), wo, wb, 0);

    dim3 g3(32, 16);
    hipLaunchKernelGGL(oproj_kernel, g3, blk, 0, stream, Aw, wb, out);
  }
}

// Round 9
// 190.045 us; speedup vs baseline: 1.1642x; 1.0085x over previous
//
#include <hip/hip_runtime.h>
#include <cstdint>
#include <cstddef>

#define D_MODEL 1024
#define NHEADS  16
#define DK      64
#define SEQ     2048
#define NBATCH  2

#define NEG_BIG (-1e30f)

typedef __attribute__((ext_vector_type(8))) short bf16x8;
typedef __attribute__((ext_vector_type(4))) short bf16x4;
typedef __attribute__((ext_vector_type(4))) float f32x4;

#if defined(__AMDGCN__)
#define SETPRIO(p) __builtin_amdgcn_s_setprio(p)
#else
#define SETPRIO(p)
#endif

// Host pass: amdgcn builtins unavailable -> guard on __AMDGCN__.
__device__ inline f32x4 mfma16x16x16(bf16x4 a, bf16x4 b, f32x4 c) {
#if defined(__AMDGCN__)
# if __has_builtin(__builtin_amdgcn_mfma_f32_16x16x16_bf16)
  return __builtin_amdgcn_mfma_f32_16x16x16_bf16(a, b, c, 0, 0, 0);
# else
  return __builtin_amdgcn_mfma_f32_16x16x16bf16_1k(a, b, c, 0, 0, 0);
# endif
#else
  (void)a; (void)b;
  return c;
#endif
}

__device__ inline void gll16(const unsigned short* g, unsigned short* l) {
#if defined(__AMDGCN__)
  __builtin_amdgcn_global_load_lds(
      (const __attribute__((address_space(1))) void*)g,
      (__attribute__((address_space(3))) void*)l, 16, 0, 0);
#else
  (void)g; (void)l;
#endif
}

__device__ inline unsigned short f2bf(float f) {
  unsigned int u = __float_as_uint(f);
  u += 0x7fffu + ((u >> 16) & 1u);   // round-to-nearest-even
  return (unsigned short)(u >> 16);
}

// ---------------------------------------------------------------------------
// Per-block dtype sniff + convert-8-elements helper (shared by cvt2/cvt3).
// ---------------------------------------------------------------------------
__device__ __forceinline__ void cvt_block(const void* src,
                                          unsigned short* dst, int i0) {
  const unsigned short* sp =
      (const unsigned short*)src + (size_t)i0 * 8 + threadIdx.x * 8;
  int cnt = 0;
#pragma unroll
  for (int j = 0; j < 8; j += 2) {
    const unsigned int u = sp[j];
    cnt += (((u >> 7) & 0xFFu) >= 0x84u) ? 1 : 0;
  }
  __shared__ int red[256];
  red[threadIdx.x] = cnt;
  __syncthreads();
  for (int s = 128; s > 0; s >>= 1) {
    if (threadIdx.x < s) red[threadIdx.x] += red[threadIdx.x + s];
    __syncthreads();
  }
  const bool isf32 = red[0] > 64;

  const int i = i0 + threadIdx.x;
  if (isf32) {
    const float4* s = (const float4*)src;
    float4 a = s[2 * i], b = s[2 * i + 1];
    uint4 r;
    r.x = (unsigned)f2bf(a.x) | ((unsigned)f2bf(a.y) << 16);
    r.y = (unsigned)f2bf(a.z) | ((unsigned)f2bf(a.w) << 16);
    r.z = (unsigned)f2bf(b.x) | ((unsigned)f2bf(b.y) << 16);
    r.w = (unsigned)f2bf(b.z) | ((unsigned)f2bf(b.w) << 16);
    ((uint4*)dst)[i] = r;
  } else {
    ((uint4*)dst)[i] = ((const uint4*)src)[i];
  }
}

// Two-buffer canonicalize (fallback path when workspace is tight).
__global__ __launch_bounds__(256) void cvt2_kernel(
    const void* __restrict__ srcA, unsigned short* __restrict__ dstA, int n8A,
    const void* __restrict__ srcB, unsigned short* __restrict__ dstB, int n8B) {
  const int bi = blockIdx.x;
  const int nblkA = n8A >> 8;
  (void)n8B;
  if (bi < nblkA) cvt_block(srcA, dstA, bi << 8);
  else            cvt_block(srcB, dstB, (bi - nblkA) << 8);
}

// Three-buffer canonicalize: x + wqkv + wo in ONE dispatch.
__global__ __launch_bounds__(256) void cvt3_kernel(
    const void* __restrict__ srcA, unsigned short* __restrict__ dstA, int n8A,
    const void* __restrict__ srcB, unsigned short* __restrict__ dstB, int n8B,
    const void* __restrict__ srcC, unsigned short* __restrict__ dstC) {
  const int bi = blockIdx.x;
  const int nblkA = n8A >> 8;
  const int nblkB = n8B >> 8;
  if (bi < nblkA)               cvt_block(srcA, dstA, bi << 8);
  else if (bi < nblkA + nblkB)  cvt_block(srcB, dstB, (bi - nblkA) << 8);
  else                          cvt_block(srcC, dstC, (bi - nblkA - nblkB) << 8);
}

// ---------------------------------------------------------------------------
// 128 x (NF*32) tile GEMM mainloop, transposed-C, BK=64, async staging with
// SOURCE-PERMUTED global_load_lds. LDS rows of 128B: As[128][64],
// Bs[NF*32][64] (bf16). 16 K-iterations.
// ---------------------------------------------------------------------------
template <int NF>
__device__ inline void gemm_bt_t(const unsigned short* __restrict__ A,
                                 const unsigned short* __restrict__ W,
                                 int m0, int n0,
                                 unsigned short* As, unsigned short* Bs,
                                 f32x4 (&acc)[NF][4]) {
  const int t    = threadIdx.x;
  const int lane = t & 63;
  const int w    = t >> 6;
  const int wm   = (w >> 1) * 64;        // token offset
  const int wn   = (w & 1) * (NF * 16);  // feature offset
  const int frow = lane & 15;
  const int q4   = lane >> 4;            // granule base (0..3)

  for (int ft = 0; ft < NF; ++ft)
    for (int tt = 0; tt < 4; ++tt)
      acc[ft][tt] = (f32x4){0.f, 0.f, 0.f, 0.f};

  const int srow  = t >> 3;         // 0..31 (row within 32-row chunk)
  const int gslot = t & 7;          // dest granule slot

  for (int k0 = 0; k0 < 1024; k0 += 64) {
    __syncthreads();
#pragma unroll
    for (int c = 0; c < 4; ++c) {   // A: 4 chunks x 32 rows
      const int row = c * 32 + srow;
      const int gsrc = gslot ^ (row & 7);
      gll16(A + (size_t)(m0 + row) * 1024 + k0 + gsrc * 8,
            As + ((size_t)t + 256 * c) * 8);
    }
#pragma unroll
    for (int c = 0; c < NF; ++c) {  // B: NF chunks x 32 rows
      const int row = c * 32 + srow;
      const int gsrc = gslot ^ (row & 7);
      gll16(W + (size_t)(n0 + row) * 1024 + k0 + gsrc * 8,
            Bs + ((size_t)t + 256 * c) * 8);
    }
    __syncthreads();

#pragma unroll
    for (int kk = 0; kk < 2; ++kk) {
      const int gg = q4 + kk * 4;   // wanted global granule
      bf16x8 xv[4], wv[NF];
#pragma unroll
      for (int tt = 0; tt < 4; ++tt) {
        const int row = wm + tt * 16 + frow;
        xv[tt] = *(const bf16x8*)(As + row * 64 + ((gg ^ (row & 7)) << 3));
      }
#pragma unroll
      for (int ft = 0; ft < NF; ++ft) {
        const int row = wn + ft * 16 + frow;
        wv[ft] = *(const bf16x8*)(Bs + row * 64 + ((gg ^ (row & 7)) << 3));
      }
#pragma unroll
      for (int ft = 0; ft < NF; ++ft)
#pragma unroll
        for (int tt = 0; tt < 4; ++tt)
          acc[ft][tt] = __builtin_amdgcn_mfma_f32_16x16x32_bf16(wv[ft], xv[tt],
                                                                acc[ft][tt], 0, 0, 0);
    }
  }
}

// ---------------------------------------------------------------------------
// Kernel 1: QKV projection + fused RoPE. 128x128 tile (NF=4), grid 768.
// XCD-aware swizzle (T1). V is written TRANSPOSED to global ([bh][d][s]).
// ---------------------------------------------------------------------------
__global__ __launch_bounds__(256) void qkv_rope_kernel(
    const unsigned short* __restrict__ x,
    const unsigned short* __restrict__ wqkv,
    unsigned short* __restrict__ Qw, unsigned short* __restrict__ Kw,
    unsigned short* __restrict__ Vw) {
  __shared__ __align__(16) unsigned short As[128 * 64];
  __shared__ __align__(16) unsigned short Bs[128 * 64];
  f32x4 acc[4][4];
  const int lin = blockIdx.y * 32 + blockIdx.x;   // 0..767
  const int c8  = lin & 7;                        // XCD (round-robin)
  const int i   = lin >> 3;                       // 0..95
  const int m0  = (c8 * 4 + (i & 3)) * 128;       // bijective remap
  const int n0  = (i >> 2) * 128;
  gemm_bt_t<4>(x, wqkv, m0, n0, As, Bs, acc);

  const int t = threadIdx.x, lane = t & 63, w = t >> 6;
  const int wm = (w >> 1) * 64, wn = (w & 1) * 64;
  const int i16 = lane & 15, q4 = lane >> 4;
  const int part = n0 >> 10;               // block-uniform
  const float LN_THETA_OVER_HALF = 0.2878231366242558f;  // ln(10000)/32

#pragma unroll
  for (int ft = 0; ft < 4; ++ft) {
    const int nb0 = n0 + wn + ft * 16 + (q4 << 2);  // 4 consecutive features
    const int h  = (nb0 >> 6) & 15;
    const int d0 = nb0 & 63;
    const float invf0 = __expf(-(float)(d0 >> 1) * LN_THETA_OVER_HALF);
    const float invf1 = __expf(-(float)((d0 >> 1) + 1) * LN_THETA_OVER_HALF);
#pragma unroll
    for (int tt = 0; tt < 4; ++tt) {
      const int m = m0 + wm + tt * 16 + i16;
      const int b = m >> 11, s = m & 2047;
      float v0 = acc[ft][tt][0], v1 = acc[ft][tt][1];
      float v2 = acc[ft][tt][2], v3 = acc[ft][tt][3];
      if (part < 2) {
        float sn0, cs0, sn1, cs1;
        __sincosf((float)s * invf0, &sn0, &cs0);
        __sincosf((float)s * invf1, &sn1, &cs1);
        const float r0 = v0 * cs0 - v1 * sn0;
        const float r1 = v0 * sn0 + v1 * cs0;
        const float r2 = v2 * cs1 - v3 * sn1;
        const float r3 = v2 * sn1 + v3 * cs1;
        v0 = r0; v1 = r1; v2 = r2; v3 = r3;
        if (part == 0) { v0 *= 0.125f; v1 *= 0.125f; v2 *= 0.125f; v3 *= 0.125f; }
        ushort4 pk;
        pk.x = f2bf(v0); pk.y = f2bf(v1); pk.z = f2bf(v2); pk.w = f2bf(v3);
        unsigned short* dst = (part == 0) ? Qw : Kw;
        *(ushort4*)(dst + (((size_t)(b * NHEADS + h)) * SEQ + s) * DK + d0) = pk;
      } else {
        // V^T: [bh][d][s]. 4 scalar stores (coalesced 32B segments per wave).
        unsigned short* vt =
            Vw + (((size_t)(b * NHEADS + h)) * DK + d0) * SEQ + s;
        vt[0]       = f2bf(v0);
        vt[SEQ]     = f2bf(v1);
        vt[2 * SEQ] = f2bf(v2);
        vt[3 * SEQ] = f2bf(v3);
      }
    }
  }
}

// ---------------------------------------------------------------------------
// Online-softmax update (shared by single and merged steps). Identical math
// to the verified attn_step: row-max over s, rescale o by alpha, pack pf.
// ---------------------------------------------------------------------------
__device__ __forceinline__ void softmax_upd(
    const f32x4 (&s)[2][4], int q4,
    float& m_i, float& l_i, f32x4 o[4], bf16x4 (&pf)[2][4]) {
  float tm = NEG_BIG;
#pragma unroll
  for (int u = 0; u < 2; ++u)
#pragma unroll
    for (int mt = 0; mt < 4; ++mt)
#pragma unroll
      for (int r = 0; r < 4; ++r) tm = fmaxf(tm, s[u][mt][r]);
  tm = fmaxf(tm, __shfl_xor(tm, 16, 64));
  tm = fmaxf(tm, __shfl_xor(tm, 32, 64));
  const float m_new = fmaxf(m_i, tm);
  const float alpha = __expf(m_i - m_new);
  m_i = m_new;

  float ls = 0.f;
#pragma unroll
  for (int u = 0; u < 2; ++u)
#pragma unroll
    for (int mt = 0; mt < 4; ++mt) {
      float p0 = __expf(s[u][mt][0] - m_new);
      float p1 = __expf(s[u][mt][1] - m_new);
      float p2 = __expf(s[u][mt][2] - m_new);
      float p3 = __expf(s[u][mt][3] - m_new);
      ls += (p0 + p1) + (p2 + p3);
      pf[u][mt][0] = (short)f2bf(p0);
      pf[u][mt][1] = (short)f2bf(p1);
      pf[u][mt][2] = (short)f2bf(p2);
      pf[u][mt][3] = (short)f2bf(p3);
    }
  ls += __shfl_xor(ls, 16, 64);
  ls += __shfl_xor(ls, 32, 64);
  l_i = l_i * alpha + ls;

  float a4[4];
#pragma unroll
  for (int r = 0; r < 4; ++r) a4[r] = __shfl(alpha, (q4 << 2) + r, 64);
#pragma unroll
  for (int n = 0; n < 4; ++n)
#pragma unroll
    for (int r = 0; r < 4; ++r) o[n][r] *= a4[r];
}

// ---------------------------------------------------------------------------
// Single-tile attention step (B-only tail iterations). Verified structure.
// ---------------------------------------------------------------------------
__device__ __forceinline__ void attn_step(
    const unsigned short* Ks0, const unsigned short* Ks1,
    const unsigned short* Vt0, const unsigned short* Vt1,
    bf16x8 qf0, bf16x8 qf1, int i16, int q4, int w,
    int q0t, int kt2, bool domask,
    float& m_i, float& l_i, f32x4 o_acc[4]) {
  f32x4 s_acc[2][4];
  SETPRIO(1);
#pragma unroll
  for (int u = 0; u < 2; ++u) {
    const unsigned short* Ksu = u ? Ks1 : Ks0;
#pragma unroll
    for (int mt = 0; mt < 4; ++mt) {
      const int key = mt * 16 + i16;
      const int k7 = key & 7;
      bf16x8 a0 = *(const bf16x8*)(Ksu + key * 64 + ((q4 ^ k7) << 3));
      bf16x8 a1 = *(const bf16x8*)(Ksu + key * 64 + (((4 + q4) ^ k7) << 3));
      f32x4 acc = (f32x4){0.f, 0.f, 0.f, 0.f};
      acc = __builtin_amdgcn_mfma_f32_16x16x32_bf16(a0, qf0, acc, 0, 0, 0);
      acc = __builtin_amdgcn_mfma_f32_16x16x32_bf16(a1, qf1, acc, 0, 0, 0);
      s_acc[u][mt] = acc;
    }
  }
  SETPRIO(0);

  if (domask) {
    const int qrow = q0t + w * 16 + i16;
#pragma unroll
    for (int u = 0; u < 2; ++u) {
      const int kb2 = (kt2 + u) * 64 + q4 * 4;
#pragma unroll
      for (int mt = 0; mt < 4; ++mt)
#pragma unroll
        for (int r = 0; r < 4; ++r)
          if (kb2 + mt * 16 + r > qrow) s_acc[u][mt][r] = NEG_BIG;
    }
  }

  bf16x4 pf[2][4];
  softmax_upd(s_acc, q4, m_i, l_i, o_acc, pf);

  SETPRIO(1);
#pragma unroll
  for (int u = 0; u < 2; ++u) {
    const unsigned short* Vtu = u ? Vt1 : Vt0;
#pragma unroll
    for (int mt = 0; mt < 4; ++mt) {
#pragma unroll
      for (int nt = 0; nt < 4; ++nt) {
        const int dk = nt * 16 + i16;
        const int slot = ((mt << 1) | (q4 >> 1)) ^ (dk & 7);
        bf16x4 vb = *(const bf16x4*)(Vtu + dk * 64 + (slot << 3) + ((q4 & 1) << 2));
        o_acc[nt] = mfma16x16x16(pf[u][mt], vb, o_acc[nt]);
      }
    }
  }
  SETPRIO(0);
}

// ---------------------------------------------------------------------------
// MERGED two-tile step: the K fragments (a0,a1) and V fragments (vb) are
// loaded ONCE and feed both tiles' MFMAs -> halves LDS read traffic (the
// measured bottleneck: ~512KB LDS reads/CU/iter ~= 2.6us port floor).
// Only tile A can hit its causal boundary here (npairA < npairB always).
// ---------------------------------------------------------------------------
__device__ __forceinline__ void attn_step2(
    const unsigned short* Ks0, const unsigned short* Ks1,
    const unsigned short* Vt0, const unsigned short* Vt1,
    bf16x8 qfB0, bf16x8 qfB1, bf16x8 qfA0, bf16x8 qfA1,
    int i16, int q4, int w, int q0A, int kt2, bool domaskA,
    float& mB, float& lB, f32x4 oB[4],
    float& mA, float& lA, f32x4 oA[4]) {
  f32x4 sB[2][4], sA[2][4];
  SETPRIO(1);
#pragma unroll
  for (int u = 0; u < 2; ++u) {
    const unsigned short* Ksu = u ? Ks1 : Ks0;
#pragma unroll
    for (int mt = 0; mt < 4; ++mt) {
      const int key = mt * 16 + i16;
      const int k7 = key & 7;
      bf16x8 a0 = *(const bf16x8*)(Ksu + key * 64 + ((q4 ^ k7) << 3));
      bf16x8 a1 = *(const bf16x8*)(Ksu + key * 64 + (((4 + q4) ^ k7) << 3));
      f32x4 ab = (f32x4){0.f, 0.f, 0.f, 0.f};
      ab = __builtin_amdgcn_mfma_f32_16x16x32_bf16(a0, qfB0, ab, 0, 0, 0);
      ab = __builtin_amdgcn_mfma_f32_16x16x32_bf16(a1, qfB1, ab, 0, 0, 0);
      sB[u][mt] = ab;
      f32x4 aa = (f32x4){0.f, 0.f, 0.f, 0.f};
      aa = __builtin_amdgcn_mfma_f32_16x16x32_bf16(a0, qfA0, aa, 0, 0, 0);
      aa = __builtin_amdgcn_mfma_f32_16x16x32_bf16(a1, qfA1, aa, 0, 0, 0);
      sA[u][mt] = aa;
    }
  }
  SETPRIO(0);

  if (domaskA) {
    const int qrow = q0A + w * 16 + i16;
#pragma unroll
    for (int u = 0; u < 2; ++u) {
      const int kb2 = (kt2 + u) * 64 + q4 * 4;
#pragma unroll
      for (int mt = 0; mt < 4; ++mt)
#pragma unroll
        for (int r = 0; r < 4; ++r)
          if (kb2 + mt * 16 + r > qrow) sA[u][mt][r] = NEG_BIG;
    }
  }

  bf16x4 pfB[2][4], pfA[2][4];
  softmax_upd(sB, q4, mB, lB, oB, pfB);
  softmax_upd(sA, q4, mA, lA, oA, pfA);

  SETPRIO(1);
#pragma unroll
  for (int u = 0; u < 2; ++u) {
    const unsigned short* Vtu = u ? Vt1 : Vt0;
#pragma unroll
    for (int mt = 0; mt < 4; ++mt) {
#pragma unroll
      for (int nt = 0; nt < 4; ++nt) {
        const int dk = nt * 16 + i16;
        const int slot = ((mt << 1) | (q4 >> 1)) ^ (dk & 7);
        bf16x4 vb = *(const bf16x4*)(Vtu + dk * 64 + (slot << 3) + ((q4 & 1) << 2));
        oB[nt] = mfma16x16x16(pfB[u][mt], vb, oB[nt]);
        oA[nt] = mfma16x16x16(pfA[u][mt], vb, oA[nt]);
      }
    }
  }
  SETPRIO(0);
}

// ---------------------------------------------------------------------------
// Kernel 2: MFMA causal flash attention, paired q-tiles, gll16 double-buffer
// staging (register-free), MERGED compute for both tiles.
// __launch_bounds__(256, 2): grid (2 blocks/CU) + 64KB LDS cap occupancy at
// 2 waves/SIMD no matter what, so give the allocator the full 256-VGPR
// budget (the R4/R7 spills came from the allocator targeting unreachable
// higher occupancy).  grid = (SEQ/128, B*H).
// ---------------------------------------------------------------------------
__global__ __launch_bounds__(256, 2) void attn_mfma_kernel(
    const unsigned short* __restrict__ Q, const unsigned short* __restrict__ K,
    const unsigned short* __restrict__ VT, unsigned short* __restrict__ O) {
  __shared__ __align__(16) unsigned short Ks[2][2][64 * 64];  // [buf][half]
  __shared__ __align__(16) unsigned short Vt[2][2][64 * 64];  // [buf][half]

  const int t = threadIdx.x, w = t >> 6, lane = t & 63;
  const int i16 = lane & 15, q4 = lane >> 4;
  const int bh = blockIdx.y;
  const int qbA = blockIdx.x;              // short tile: 0..15
  const int qbB = 31 - blockIdx.x;         // long tile: 16..31
  const int q0A = qbA * 64, q0B = qbB * 64;
  const size_t base = (size_t)bh * SEQ * DK;

  const int srow  = t >> 3;   // 0..31
  const int gslot = t & 7;

  auto stage = [&](int p, int buf) {
#pragma unroll
    for (int c = 0; c < 4; ++c) {
      const int row = srow + 32 * c;          // 0..127 (half u = row>>6)
      const int gs  = gslot ^ (row & 7);
      gll16(K + base + (size_t)(p * 128 + row) * DK + gs * 8,
            &Ks[buf][0][0] + ((size_t)t + 256 * c) * 8);
    }
#pragma unroll
    for (int c = 0; c < 4; ++c) {
      const int row = srow + 32 * c;          // u = row>>6, dk = row&63
      const int gs  = gslot ^ (row & 7);      // dk&7 == row&7
      gll16(VT + base + (size_t)(row & 63) * SEQ
               + p * 128 + (row >> 6) * 64 + gs * 8,
            &Vt[buf][0][0] + ((size_t)t + 256 * c) * 8);
    }
  };

  bf16x8 qfA0, qfA1, qfB0, qfB1;
  {
    const unsigned short* qpA = Q + base + (size_t)(q0A + w * 16 + i16) * DK + q4 * 8;
    qfA0 = *(const bf16x8*)(qpA);
    qfA1 = *(const bf16x8*)(qpA + 32);
    const unsigned short* qpB = Q + base + (size_t)(q0B + w * 16 + i16) * DK + q4 * 8;
    qfB0 = *(const bf16x8*)(qpB);
    qfB1 = *(const bf16x8*)(qpB + 32);
  }

  f32x4 oA[4], oB[4];
#pragma unroll
  for (int n = 0; n < 4; ++n) {
    oA[n] = (f32x4){0.f, 0.f, 0.f, 0.f};
    oB[n] = (f32x4){0.f, 0.f, 0.f, 0.f};
  }
  float mA = NEG_BIG, lA = 0.f, mB = NEG_BIG, lB = 0.f;

  const int npairA = (qbA >> 1) + 1;
  const int npairB = (qbB >> 1) + 1;   // npairA < npairB always (qbA <= 15)

  stage(0, 0);                         // prologue

  for (int pr = 0; pr < npairB; ++pr) {
    const int kt2 = pr * 2;
    const int cb = pr & 1;
    __syncthreads();                   // drains stage(pr) -> buf cb ready
    if (pr + 1 < npairB) stage(pr + 1, cb ^ 1);   // async; hides under compute

    if (pr < npairA) {
      // merged: shared K/V fragment loads feed both tiles (B never masks here)
      attn_step2(Ks[cb][0], Ks[cb][1], Vt[cb][0], Vt[cb][1],
                 qfB0, qfB1, qfA0, qfA1, i16, q4, w,
                 q0A, kt2, pr == npairA - 1,
                 mB, lB, oB, mA, lA, oA);
    } else {
      attn_step(Ks[cb][0], Ks[cb][1], Vt[cb][0], Vt[cb][1], qfB0, qfB1,
                i16, q4, w, q0B, kt2, pr == npairB - 1, mB, lB, oB);
    }
  }

  // ---- epilogues ----
  const int b = bh >> 4, h = bh & 15;
#pragma unroll
  for (int r = 0; r < 4; ++r) {
    const float lrA = __shfl(lA, (q4 << 2) + r, 64);
    const float lrB = __shfl(lB, (q4 << 2) + r, 64);
    const float invA = 1.0f / lrA;
    const float invB = 1.0f / lrB;
    const int sA = q0A + w * 16 + (q4 << 2) + r;
    const int sB = q0B + w * 16 + (q4 << 2) + r;
#pragma unroll
    for (int nt = 0; nt < 4; ++nt) {
      const int dk = nt * 16 + i16;
      O[((size_t)(b * SEQ + sA)) * D_MODEL + h * DK + dk] = f2bf(oA[nt][r] * invA);
      O[((size_t)(b * SEQ + sB)) * D_MODEL + h * DK + dk] = f2bf(oB[nt][r] * invB);
    }
  }
}

// ---------------------------------------------------------------------------
// Kernel 3: output projection -> fp32, float4 packed stores. grid (32, 16).
// NF=2; XCD-aware swizzle (same scheme as qkv, 512 blocks, 512%8==0).
// ---------------------------------------------------------------------------
__global__ __launch_bounds__(256) void oproj_kernel(
    const unsigned short* __restrict__ ain, const unsigned short* __restrict__ wo,
    float* __restrict__ out) {
  __shared__ __align__(16) unsigned short As[128 * 64];
  __shared__ __align__(16) unsigned short Bs[64 * 64];
  f32x4 acc[2][4];
  const int lin = blockIdx.y * 32 + blockIdx.x;   // 0..511
  const int c8  = lin & 7;
  const int i   = lin >> 3;                       // 0..63
  const int m0  = (c8 * 4 + (i & 3)) * 128;
  const int n0  = (i >> 2) * 64;
  gemm_bt_t<2>(ain, wo, m0, n0, As, Bs, acc);

  const int t = threadIdx.x, lane = t & 63, w = t >> 6;
  const int wm = (w >> 1) * 64, wn = (w & 1) * 32;
  const int i16 = lane & 15, q4 = lane >> 4;
#pragma unroll
  for (int ft = 0; ft < 2; ++ft) {
    const int nb0 = n0 + wn + ft * 16 + (q4 << 2);
#pragma unroll
    for (int tt = 0; tt < 4; ++tt) {
      const int m = m0 + wm + tt * 16 + i16;
      float4 v;
      v.x = acc[ft][tt][0]; v.y = acc[ft][tt][1];
      v.z = acc[ft][tt][2]; v.w = acc[ft][tt][3];
      *(float4*)(out + (size_t)m * D_MODEL + nb0) = v;
    }
  }
}

// ---------------------------------------------------------------------------
extern "C" void kernel_launch(void* const* d_in, const int* in_sizes, int n_in,
                              void* d_out, int out_size, void* d_ws, size_t ws_size,
                              hipStream_t stream) {
  const void* x    = d_in[0];
  const void* wqkv = d_in[2];
  const void* wo   = d_in[3];
  float* out = (float*)d_out;

  const size_t NTOK  = (size_t)NBATCH * SEQ * D_MODEL;  // 4,194,304 elements
  const size_t NWQKV = (size_t)3 * D_MODEL * D_MODEL;   // 3,145,728
  const size_t NWO   = (size_t)D_MODEL * D_MODEL;       // 1,048,576

  unsigned short* base = (unsigned short*)((char*)d_ws + 16);
  unsigned short* Qw = base;                 // NTOK
  unsigned short* Kw = Qw + NTOK;            // NTOK
  unsigned short* Vw = Kw + NTOK;            // NTOK (V^T layout [bh][d][s])
  unsigned short* Aw = Vw + NTOK;            // NTOK (aliases xb; xb dead before attn writes)
  unsigned short* xb = Aw;                   // canonical bf16 x
  unsigned short* wq = Aw + NTOK;            // NWQKV

  dim3 blk(256);

  // Workspace for a SEPARATE wb (no aliasing) needs:
  const size_t need = 16 + (4 * NTOK + NWQKV + NWO) * sizeof(unsigned short);

  if (ws_size >= need) {
    // Single canonicalization dispatch: x + wqkv + wo.
    unsigned short* wb = wq + NWQKV;
    hipLaunchKernelGGL(cvt3_kernel, dim3(4096), blk, 0, stream,
                       x, xb, (int)(NTOK / 8), wqkv, wq, (int)(NWQKV / 8),
                       wo, wb);

    dim3 g1(32, 24);
    hipLaunchKernelGGL(qkv_rope_kernel, g1, blk, 0, stream, xb, wq, Qw, Kw, Vw);

    dim3 g2(SEQ / 128, NBATCH * NHEADS);
    hipLaunchKernelGGL(attn_mfma_kernel, g2, blk, 0, stream, Qw, Kw, Vw, Aw);

    dim3 g3(32, 16);
    hipLaunchKernelGGL(oproj_kernel, g3, blk, 0, stream, Aw, wb, out);
  } else {
    // Fallback: wb aliases wq, converted after qkv.
    unsigned short* wb = wq;
    hipLaunchKernelGGL(cvt2_kernel, dim3(3584), blk, 0, stream,
                       x, xb, (int)(NTOK / 8), wqkv, wq, (int)(NWQKV / 8));

    dim3 g1(32, 24);
    hipLaunchKernelGGL(qkv_rope_kernel, g1, blk, 0, stream, xb, wq, Qw, Kw, Vw);

    dim3 g2(SEQ / 128, NBATCH * NHEADS);
    hipLaunchKernelGGL(attn_mfma_kernel, g2, blk, 0, stream, Qw, Kw, Vw, Aw);

    hipLaunchKernelGGL(cvt2_kernel, dim3(512), blk, 0, stream,
                       wo, wb, (int)(NWO / 8), wo, wb, 0);

    dim3 g3(32, 16);
    hipLaunchKernelGGL(oproj_kernel, g3, blk, 0, stream, Aw, wb, out);
  }
}

// Round 11
// 181.555 us; speedup vs baseline: 1.2186x; 1.0468x over previous
//
#include <hip/hip_runtime.h>
#include <cstdint>
#include <cstddef>
#include <cmath>

#define D_MODEL 1024
#define NHEADS  16
#define DK      64
#define SEQ     2048
#define NBATCH  2

#define NEG_BIG (-1e30f)

typedef __attribute__((ext_vector_type(8))) short bf16x8;
typedef __attribute__((ext_vector_type(4))) short bf16x4;
typedef __attribute__((ext_vector_type(4))) float f32x4;

#if defined(__AMDGCN__)
#define SETPRIO(p) __builtin_amdgcn_s_setprio(p)
#else
#define SETPRIO(p)
#endif

// Native base-2 exp (v_exp_f32). __exp2f does NOT exist in HIP device code
// (R10 compile failure); use the amdgcn builtin with a portable fallback.
__device__ __forceinline__ float fexp2(float x) {
#if defined(__AMDGCN__) && __has_builtin(__builtin_amdgcn_exp2f)
  return __builtin_amdgcn_exp2f(x);
#else
  return exp2f(x);
#endif
}

// Host pass: amdgcn builtins unavailable -> guard on __AMDGCN__.
__device__ inline f32x4 mfma16x16x16(bf16x4 a, bf16x4 b, f32x4 c) {
#if defined(__AMDGCN__)
# if __has_builtin(__builtin_amdgcn_mfma_f32_16x16x16_bf16)
  return __builtin_amdgcn_mfma_f32_16x16x16_bf16(a, b, c, 0, 0, 0);
# else
  return __builtin_amdgcn_mfma_f32_16x16x16bf16_1k(a, b, c, 0, 0, 0);
# endif
#else
  (void)a; (void)b;
  return c;
#endif
}

__device__ inline void gll16(const unsigned short* g, unsigned short* l) {
#if defined(__AMDGCN__)
  __builtin_amdgcn_global_load_lds(
      (const __attribute__((address_space(1))) void*)g,
      (__attribute__((address_space(3))) void*)l, 16, 0, 0);
#else
  (void)g; (void)l;
#endif
}

__device__ inline unsigned short f2bf(float f) {
  unsigned int u = __float_as_uint(f);
  u += 0x7fffu + ((u >> 16) & 1u);   // round-to-nearest-even
  return (unsigned short)(u >> 16);
}

// Pack two floats to packed bf16 (HW RNE) - replaces 2x f2bf (6 VALU ops).
__device__ __forceinline__ unsigned cvtpk_bf16(float lo, float hi) {
#if defined(__AMDGCN__)
  unsigned r;
  asm("v_cvt_pk_bf16_f32 %0, %1, %2" : "=v"(r) : "v"(lo), "v"(hi));
  return r;
#else
  return (unsigned)f2bf(lo) | ((unsigned)f2bf(hi) << 16);
#endif
}

// ---------------------------------------------------------------------------
// Per-block dtype sniff + convert-8-elements helper (shared by cvt2/cvt3).
// ---------------------------------------------------------------------------
__device__ __forceinline__ void cvt_block(const void* src,
                                          unsigned short* dst, int i0) {
  const unsigned short* sp =
      (const unsigned short*)src + (size_t)i0 * 8 + threadIdx.x * 8;
  int cnt = 0;
#pragma unroll
  for (int j = 0; j < 8; j += 2) {
    const unsigned int u = sp[j];
    cnt += (((u >> 7) & 0xFFu) >= 0x84u) ? 1 : 0;
  }
  __shared__ int red[256];
  red[threadIdx.x] = cnt;
  __syncthreads();
  for (int s = 128; s > 0; s >>= 1) {
    if (threadIdx.x < s) red[threadIdx.x] += red[threadIdx.x + s];
    __syncthreads();
  }
  const bool isf32 = red[0] > 64;

  const int i = i0 + threadIdx.x;
  if (isf32) {
    const float4* s = (const float4*)src;
    float4 a = s[2 * i], b = s[2 * i + 1];
    uint4 r;
    r.x = (unsigned)f2bf(a.x) | ((unsigned)f2bf(a.y) << 16);
    r.y = (unsigned)f2bf(a.z) | ((unsigned)f2bf(a.w) << 16);
    r.z = (unsigned)f2bf(b.x) | ((unsigned)f2bf(b.y) << 16);
    r.w = (unsigned)f2bf(b.z) | ((unsigned)f2bf(b.w) << 16);
    ((uint4*)dst)[i] = r;
  } else {
    ((uint4*)dst)[i] = ((const uint4*)src)[i];
  }
}

// Two-buffer canonicalize (fallback path when workspace is tight).
__global__ __launch_bounds__(256) void cvt2_kernel(
    const void* __restrict__ srcA, unsigned short* __restrict__ dstA, int n8A,
    const void* __restrict__ srcB, unsigned short* __restrict__ dstB, int n8B) {
  const int bi = blockIdx.x;
  const int nblkA = n8A >> 8;
  (void)n8B;
  if (bi < nblkA) cvt_block(srcA, dstA, bi << 8);
  else            cvt_block(srcB, dstB, (bi - nblkA) << 8);
}

// Three-buffer canonicalize: x + wqkv + wo in ONE dispatch.
__global__ __launch_bounds__(256) void cvt3_kernel(
    const void* __restrict__ srcA, unsigned short* __restrict__ dstA, int n8A,
    const void* __restrict__ srcB, unsigned short* __restrict__ dstB, int n8B,
    const void* __restrict__ srcC, unsigned short* __restrict__ dstC) {
  const int bi = blockIdx.x;
  const int nblkA = n8A >> 8;
  const int nblkB = n8B >> 8;
  if (bi < nblkA)               cvt_block(srcA, dstA, bi << 8);
  else if (bi < nblkA + nblkB)  cvt_block(srcB, dstB, (bi - nblkA) << 8);
  else                          cvt_block(srcC, dstC, (bi - nblkA - nblkB) << 8);
}

// ---------------------------------------------------------------------------
// 128 x (NF*32) tile GEMM mainloop, transposed-C, BK=64, async staging with
// SOURCE-PERMUTED global_load_lds. LDS rows of 128B: As[128][64],
// Bs[NF*32][64] (bf16). 16 K-iterations.
// ---------------------------------------------------------------------------
template <int NF>
__device__ inline void gemm_bt_t(const unsigned short* __restrict__ A,
                                 const unsigned short* __restrict__ W,
                                 int m0, int n0,
                                 unsigned short* As, unsigned short* Bs,
                                 f32x4 (&acc)[NF][4]) {
  const int t    = threadIdx.x;
  const int lane = t & 63;
  const int w    = t >> 6;
  const int wm   = (w >> 1) * 64;        // token offset
  const int wn   = (w & 1) * (NF * 16);  // feature offset
  const int frow = lane & 15;
  const int q4   = lane >> 4;            // granule base (0..3)

  for (int ft = 0; ft < NF; ++ft)
    for (int tt = 0; tt < 4; ++tt)
      acc[ft][tt] = (f32x4){0.f, 0.f, 0.f, 0.f};

  const int srow  = t >> 3;         // 0..31 (row within 32-row chunk)
  const int gslot = t & 7;          // dest granule slot

  for (int k0 = 0; k0 < 1024; k0 += 64) {
    __syncthreads();
#pragma unroll
    for (int c = 0; c < 4; ++c) {   // A: 4 chunks x 32 rows
      const int row = c * 32 + srow;
      const int gsrc = gslot ^ (row & 7);
      gll16(A + (size_t)(m0 + row) * 1024 + k0 + gsrc * 8,
            As + ((size_t)t + 256 * c) * 8);
    }
#pragma unroll
    for (int c = 0; c < NF; ++c) {  // B: NF chunks x 32 rows
      const int row = c * 32 + srow;
      const int gsrc = gslot ^ (row & 7);
      gll16(W + (size_t)(n0 + row) * 1024 + k0 + gsrc * 8,
            Bs + ((size_t)t + 256 * c) * 8);
    }
    __syncthreads();

#pragma unroll
    for (int kk = 0; kk < 2; ++kk) {
      const int gg = q4 + kk * 4;   // wanted global granule
      bf16x8 xv[4], wv[NF];
#pragma unroll
      for (int tt = 0; tt < 4; ++tt) {
        const int row = wm + tt * 16 + frow;
        xv[tt] = *(const bf16x8*)(As + row * 64 + ((gg ^ (row & 7)) << 3));
      }
#pragma unroll
      for (int ft = 0; ft < NF; ++ft) {
        const int row = wn + ft * 16 + frow;
        wv[ft] = *(const bf16x8*)(Bs + row * 64 + ((gg ^ (row & 7)) << 3));
      }
#pragma unroll
      for (int ft = 0; ft < NF; ++ft)
#pragma unroll
        for (int tt = 0; tt < 4; ++tt)
          acc[ft][tt] = __builtin_amdgcn_mfma_f32_16x16x32_bf16(wv[ft], xv[tt],
                                                                acc[ft][tt], 0, 0, 0);
    }
  }
}

// ---------------------------------------------------------------------------
// Kernel 1: QKV projection + fused RoPE. 128x128 tile (NF=4), grid 768.
// XCD-aware swizzle (T1). V is written TRANSPOSED to global ([bh][d][s]).
// Q is pre-scaled by 0.125*log2(e) so attention softmax runs in exp2 domain
// (p = exp2(s-m) = native v_exp_f32, no per-exp multiply).
// ---------------------------------------------------------------------------
__global__ __launch_bounds__(256) void qkv_rope_kernel(
    const unsigned short* __restrict__ x,
    const unsigned short* __restrict__ wqkv,
    unsigned short* __restrict__ Qw, unsigned short* __restrict__ Kw,
    unsigned short* __restrict__ Vw) {
  __shared__ __align__(16) unsigned short As[128 * 64];
  __shared__ __align__(16) unsigned short Bs[128 * 64];
  f32x4 acc[4][4];
  const int lin = blockIdx.y * 32 + blockIdx.x;   // 0..767
  const int c8  = lin & 7;                        // XCD (round-robin)
  const int i   = lin >> 3;                       // 0..95
  const int m0  = (c8 * 4 + (i & 3)) * 128;       // bijective remap
  const int n0  = (i >> 2) * 128;
  gemm_bt_t<4>(x, wqkv, m0, n0, As, Bs, acc);

  const int t = threadIdx.x, lane = t & 63, w = t >> 6;
  const int wm = (w >> 1) * 64, wn = (w & 1) * 64;
  const int i16 = lane & 15, q4 = lane >> 4;
  const int part = n0 >> 10;               // block-uniform
  const float LN_THETA_OVER_HALF = 0.2878231366242558f;  // ln(10000)/32
  const float SCALE_L2E = 0.18033688011112042f;          // 0.125 * log2(e)

#pragma unroll
  for (int ft = 0; ft < 4; ++ft) {
    const int nb0 = n0 + wn + ft * 16 + (q4 << 2);  // 4 consecutive features
    const int h  = (nb0 >> 6) & 15;
    const int d0 = nb0 & 63;
    const float invf0 = __expf(-(float)(d0 >> 1) * LN_THETA_OVER_HALF);
    const float invf1 = __expf(-(float)((d0 >> 1) + 1) * LN_THETA_OVER_HALF);
#pragma unroll
    for (int tt = 0; tt < 4; ++tt) {
      const int m = m0 + wm + tt * 16 + i16;
      const int b = m >> 11, s = m & 2047;
      float v0 = acc[ft][tt][0], v1 = acc[ft][tt][1];
      float v2 = acc[ft][tt][2], v3 = acc[ft][tt][3];
      if (part < 2) {
        float sn0, cs0, sn1, cs1;
        __sincosf((float)s * invf0, &sn0, &cs0);
        __sincosf((float)s * invf1, &sn1, &cs1);
        const float r0 = v0 * cs0 - v1 * sn0;
        const float r1 = v0 * sn0 + v1 * cs0;
        const float r2 = v2 * cs1 - v3 * sn1;
        const float r3 = v2 * sn1 + v3 * cs1;
        v0 = r0; v1 = r1; v2 = r2; v3 = r3;
        if (part == 0) {
          v0 *= SCALE_L2E; v1 *= SCALE_L2E; v2 *= SCALE_L2E; v3 *= SCALE_L2E;
        }
        ushort4 pk;
        pk.x = f2bf(v0); pk.y = f2bf(v1); pk.z = f2bf(v2); pk.w = f2bf(v3);
        unsigned short* dst = (part == 0) ? Qw : Kw;
        *(ushort4*)(dst + (((size_t)(b * NHEADS + h)) * SEQ + s) * DK + d0) = pk;
      } else {
        // V^T: [bh][d][s]. 4 scalar stores (coalesced 32B segments per wave).
        unsigned short* vt =
            Vw + (((size_t)(b * NHEADS + h)) * DK + d0) * SEQ + s;
        vt[0]       = f2bf(v0);
        vt[SEQ]     = f2bf(v1);
        vt[2 * SEQ] = f2bf(v2);
        vt[3 * SEQ] = f2bf(v3);
      }
    }
  }
}

// ---------------------------------------------------------------------------
// Online-softmax update in EXP2 DOMAIN (scores pre-scaled by log2e in qkv).
// p = exp2(s - m) — identical values to exp((S-m)/8), native v_exp_f32.
// P packed via v_cvt_pk_bf16_f32 (HW RNE, 2 floats/inst).
// ---------------------------------------------------------------------------
__device__ __forceinline__ void softmax_upd(
    const f32x4 (&s)[2][4], int q4,
    float& m_i, float& l_i, f32x4 o[4], bf16x4 (&pf)[2][4]) {
  float tm = NEG_BIG;
#pragma unroll
  for (int u = 0; u < 2; ++u)
#pragma unroll
    for (int mt = 0; mt < 4; ++mt)
#pragma unroll
      for (int r = 0; r < 4; ++r) tm = fmaxf(tm, s[u][mt][r]);
  tm = fmaxf(tm, __shfl_xor(tm, 16, 64));
  tm = fmaxf(tm, __shfl_xor(tm, 32, 64));
  const float m_new = fmaxf(m_i, tm);
  const float alpha = fexp2(m_i - m_new);
  m_i = m_new;

  float ls = 0.f;
#pragma unroll
  for (int u = 0; u < 2; ++u)
#pragma unroll
    for (int mt = 0; mt < 4; ++mt) {
      float p0 = fexp2(s[u][mt][0] - m_new);
      float p1 = fexp2(s[u][mt][1] - m_new);
      float p2 = fexp2(s[u][mt][2] - m_new);
      float p3 = fexp2(s[u][mt][3] - m_new);
      ls += (p0 + p1) + (p2 + p3);
      union { unsigned uu[2]; bf16x4 v; } pkk;
      pkk.uu[0] = cvtpk_bf16(p0, p1);
      pkk.uu[1] = cvtpk_bf16(p2, p3);
      pf[u][mt] = pkk.v;
    }
  ls += __shfl_xor(ls, 16, 64);
  ls += __shfl_xor(ls, 32, 64);
  l_i = l_i * alpha + ls;

  float a4[4];
#pragma unroll
  for (int r = 0; r < 4; ++r) a4[r] = __shfl(alpha, (q4 << 2) + r, 64);
#pragma unroll
  for (int n = 0; n < 4; ++n)
#pragma unroll
    for (int r = 0; r < 4; ++r) o[n][r] *= a4[r];
}

// ---------------------------------------------------------------------------
// Single-tile attention step (B-only tail iterations). Verified structure.
// ---------------------------------------------------------------------------
__device__ __forceinline__ void attn_step(
    const unsigned short* Ks0, const unsigned short* Ks1,
    const unsigned short* Vt0, const unsigned short* Vt1,
    bf16x8 qf0, bf16x8 qf1, int i16, int q4, int w,
    int q0t, int kt2, bool domask,
    float& m_i, float& l_i, f32x4 o_acc[4]) {
  f32x4 s_acc[2][4];
  SETPRIO(1);
#pragma unroll
  for (int u = 0; u < 2; ++u) {
    const unsigned short* Ksu = u ? Ks1 : Ks0;
#pragma unroll
    for (int mt = 0; mt < 4; ++mt) {
      const int key = mt * 16 + i16;
      const int k7 = key & 7;
      bf16x8 a0 = *(const bf16x8*)(Ksu + key * 64 + ((q4 ^ k7) << 3));
      bf16x8 a1 = *(const bf16x8*)(Ksu + key * 64 + (((4 + q4) ^ k7) << 3));
      f32x4 acc = (f32x4){0.f, 0.f, 0.f, 0.f};
      acc = __builtin_amdgcn_mfma_f32_16x16x32_bf16(a0, qf0, acc, 0, 0, 0);
      acc = __builtin_amdgcn_mfma_f32_16x16x32_bf16(a1, qf1, acc, 0, 0, 0);
      s_acc[u][mt] = acc;
    }
  }
  SETPRIO(0);

  if (domask) {
    const int qrow = q0t + w * 16 + i16;
#pragma unroll
    for (int u = 0; u < 2; ++u) {
      const int kb2 = (kt2 + u) * 64 + q4 * 4;
#pragma unroll
      for (int mt = 0; mt < 4; ++mt)
#pragma unroll
        for (int r = 0; r < 4; ++r)
          if (kb2 + mt * 16 + r > qrow) s_acc[u][mt][r] = NEG_BIG;
    }
  }

  bf16x4 pf[2][4];
  softmax_upd(s_acc, q4, m_i, l_i, o_acc, pf);

  SETPRIO(1);
#pragma unroll
  for (int u = 0; u < 2; ++u) {
    const unsigned short* Vtu = u ? Vt1 : Vt0;
#pragma unroll
    for (int mt = 0; mt < 4; ++mt) {
#pragma unroll
      for (int nt = 0; nt < 4; ++nt) {
        const int dk = nt * 16 + i16;
        const int slot = ((mt << 1) | (q4 >> 1)) ^ (dk & 7);
        bf16x4 vb = *(const bf16x4*)(Vtu + dk * 64 + (slot << 3) + ((q4 & 1) << 2));
        o_acc[nt] = mfma16x16x16(pf[u][mt], vb, o_acc[nt]);
      }
    }
  }
  SETPRIO(0);
}

// ---------------------------------------------------------------------------
// MERGED two-tile step: K/V fragments loaded once feed both tiles' MFMAs.
// ---------------------------------------------------------------------------
__device__ __forceinline__ void attn_step2(
    const unsigned short* Ks0, const unsigned short* Ks1,
    const unsigned short* Vt0, const unsigned short* Vt1,
    bf16x8 qfB0, bf16x8 qfB1, bf16x8 qfA0, bf16x8 qfA1,
    int i16, int q4, int w, int q0A, int kt2, bool domaskA,
    float& mB, float& lB, f32x4 oB[4],
    float& mA, float& lA, f32x4 oA[4]) {
  f32x4 sB[2][4], sA[2][4];
  SETPRIO(1);
#pragma unroll
  for (int u = 0; u < 2; ++u) {
    const unsigned short* Ksu = u ? Ks1 : Ks0;
#pragma unroll
    for (int mt = 0; mt < 4; ++mt) {
      const int key = mt * 16 + i16;
      const int k7 = key & 7;
      bf16x8 a0 = *(const bf16x8*)(Ksu + key * 64 + ((q4 ^ k7) << 3));
      bf16x8 a1 = *(const bf16x8*)(Ksu + key * 64 + (((4 + q4) ^ k7) << 3));
      f32x4 ab = (f32x4){0.f, 0.f, 0.f, 0.f};
      ab = __builtin_amdgcn_mfma_f32_16x16x32_bf16(a0, qfB0, ab, 0, 0, 0);
      ab = __builtin_amdgcn_mfma_f32_16x16x32_bf16(a1, qfB1, ab, 0, 0, 0);
      sB[u][mt] = ab;
      f32x4 aa = (f32x4){0.f, 0.f, 0.f, 0.f};
      aa = __builtin_amdgcn_mfma_f32_16x16x32_bf16(a0, qfA0, aa, 0, 0, 0);
      aa = __builtin_amdgcn_mfma_f32_16x16x32_bf16(a1, qfA1, aa, 0, 0, 0);
      sA[u][mt] = aa;
    }
  }
  SETPRIO(0);

  if (domaskA) {
    const int qrow = q0A + w * 16 + i16;
#pragma unroll
    for (int u = 0; u < 2; ++u) {
      const int kb2 = (kt2 + u) * 64 + q4 * 4;
#pragma unroll
      for (int mt = 0; mt < 4; ++mt)
#pragma unroll
        for (int r = 0; r < 4; ++r)
          if (kb2 + mt * 16 + r > qrow) sA[u][mt][r] = NEG_BIG;
    }
  }

  bf16x4 pfB[2][4], pfA[2][4];
  softmax_upd(sB, q4, mB, lB, oB, pfB);
  softmax_upd(sA, q4, mA, lA, oA, pfA);

  SETPRIO(1);
#pragma unroll
  for (int u = 0; u < 2; ++u) {
    const unsigned short* Vtu = u ? Vt1 : Vt0;
#pragma unroll
    for (int mt = 0; mt < 4; ++mt) {
#pragma unroll
      for (int nt = 0; nt < 4; ++nt) {
        const int dk = nt * 16 + i16;
        const int slot = ((mt << 1) | (q4 >> 1)) ^ (dk & 7);
        bf16x4 vb = *(const bf16x4*)(Vtu + dk * 64 + (slot << 3) + ((q4 & 1) << 2));
        oB[nt] = mfma16x16x16(pfB[u][mt], vb, oB[nt]);
        oA[nt] = mfma16x16x16(pfA[u][mt], vb, oA[nt]);
      }
    }
  }
  SETPRIO(0);
}

// ---------------------------------------------------------------------------
// Kernel 2: MFMA causal flash attention, paired q-tiles, gll16 double-buffer
// staging, merged compute. XCD-aware bh grouping: XCD c owns bh {4c..4c+3}
// entirely (lin%8 = XCD round-robin), so each bh's K+V (512KB; 2MB per XCD)
// stays L2-resident across its 16 qb-blocks -> gll16 staging hits L2
// (~200cy) instead of HBM (~900cy) and FETCH drops ~70->~30MB.
// Load balance unchanged: every block is exactly 17 tile-steps.
// __launch_bounds__(256, 2): occupancy is LDS/grid-capped at 2 waves/SIMD,
// so give the allocator the full register budget. grid = (16, 32).
// ---------------------------------------------------------------------------
__global__ __launch_bounds__(256, 2) void attn_mfma_kernel(
    const unsigned short* __restrict__ Q, const unsigned short* __restrict__ K,
    const unsigned short* __restrict__ VT, unsigned short* __restrict__ O) {
  __shared__ __align__(16) unsigned short Ks[2][2][64 * 64];  // [buf][half]
  __shared__ __align__(16) unsigned short Vt[2][2][64 * 64];  // [buf][half]

  const int t = threadIdx.x, w = t >> 6, lane = t & 63;
  const int i16 = lane & 15, q4 = lane >> 4;
  // XCD remap: lin%8 = XCD; XCD c owns bh 4c..4c+3; pair index iterates within.
  const int lin = blockIdx.y * 16 + blockIdx.x;   // 0..511
  const int c8  = lin & 7;
  const int j   = lin >> 3;                       // 0..63
  const int bh  = c8 * 4 + (j & 3);
  const int qbA = j >> 2;                         // 0..15
  const int qbB = 31 - qbA;                       // 16..31
  const int q0A = qbA * 64, q0B = qbB * 64;
  const size_t base = (size_t)bh * SEQ * DK;

  const int srow  = t >> 3;   // 0..31
  const int gslot = t & 7;

  auto stage = [&](int p, int buf) {
#pragma unroll
    for (int c = 0; c < 4; ++c) {
      const int row = srow + 32 * c;          // 0..127 (half u = row>>6)
      const int gs  = gslot ^ (row & 7);
      gll16(K + base + (size_t)(p * 128 + row) * DK + gs * 8,
            &Ks[buf][0][0] + ((size_t)t + 256 * c) * 8);
    }
#pragma unroll
    for (int c = 0; c < 4; ++c) {
      const int row = srow + 32 * c;          // u = row>>6, dk = row&63
      const int gs  = gslot ^ (row & 7);      // dk&7 == row&7
      gll16(VT + base + (size_t)(row & 63) * SEQ
               + p * 128 + (row >> 6) * 64 + gs * 8,
            &Vt[buf][0][0] + ((size_t)t + 256 * c) * 8);
    }
  };

  bf16x8 qfA0, qfA1, qfB0, qfB1;
  {
    const unsigned short* qpA = Q + base + (size_t)(q0A + w * 16 + i16) * DK + q4 * 8;
    qfA0 = *(const bf16x8*)(qpA);
    qfA1 = *(const bf16x8*)(qpA + 32);
    const unsigned short* qpB = Q + base + (size_t)(q0B + w * 16 + i16) * DK + q4 * 8;
    qfB0 = *(const bf16x8*)(qpB);
    qfB1 = *(const bf16x8*)(qpB + 32);
  }

  f32x4 oA[4], oB[4];
#pragma unroll
  for (int n = 0; n < 4; ++n) {
    oA[n] = (f32x4){0.f, 0.f, 0.f, 0.f};
    oB[n] = (f32x4){0.f, 0.f, 0.f, 0.f};
  }
  float mA = NEG_BIG, lA = 0.f, mB = NEG_BIG, lB = 0.f;

  const int npairA = (qbA >> 1) + 1;
  const int npairB = (qbB >> 1) + 1;   // npairA < npairB always (qbA <= 15)

  stage(0, 0);                         // prologue

  for (int pr = 0; pr < npairB; ++pr) {
    const int kt2 = pr * 2;
    const int cb = pr & 1;
    __syncthreads();                   // drains stage(pr) -> buf cb ready
    if (pr + 1 < npairB) stage(pr + 1, cb ^ 1);   // async; hides under compute

    if (pr < npairA) {
      attn_step2(Ks[cb][0], Ks[cb][1], Vt[cb][0], Vt[cb][1],
                 qfB0, qfB1, qfA0, qfA1, i16, q4, w,
                 q0A, kt2, pr == npairA - 1,
                 mB, lB, oB, mA, lA, oA);
    } else {
      attn_step(Ks[cb][0], Ks[cb][1], Vt[cb][0], Vt[cb][1], qfB0, qfB1,
                i16, q4, w, q0B, kt2, pr == npairB - 1, mB, lB, oB);
    }
  }

  // ---- epilogues ----
  const int b = bh >> 4, h = bh & 15;
#pragma unroll
  for (int r = 0; r < 4; ++r) {
    const float lrA = __shfl(lA, (q4 << 2) + r, 64);
    const float lrB = __shfl(lB, (q4 << 2) + r, 64);
    const float invA = 1.0f / lrA;
    const float invB = 1.0f / lrB;
    const int sA = q0A + w * 16 + (q4 << 2) + r;
    const int sB = q0B + w * 16 + (q4 << 2) + r;
#pragma unroll
    for (int nt = 0; nt < 4; ++nt) {
      const int dk = nt * 16 + i16;
      O[((size_t)(b * SEQ + sA)) * D_MODEL + h * DK + dk] = f2bf(oA[nt][r] * invA);
      O[((size_t)(b * SEQ + sB)) * D_MODEL + h * DK + dk] = f2bf(oB[nt][r] * invB);
    }
  }
}

// ---------------------------------------------------------------------------
// Kernel 3: output projection -> fp32, float4 packed stores. grid (32, 16).
// NF=2; XCD-aware swizzle (same scheme as qkv, 512 blocks, 512%8==0).
// ---------------------------------------------------------------------------
__global__ __launch_bounds__(256) void oproj_kernel(
    const unsigned short* __restrict__ ain, const unsigned short* __restrict__ wo,
    float* __restrict__ out) {
  __shared__ __align__(16) unsigned short As[128 * 64];
  __shared__ __align__(16) unsigned short Bs[64 * 64];
  f32x4 acc[2][4];
  const int lin = blockIdx.y * 32 + blockIdx.x;   // 0..511
  const int c8  = lin & 7;
  const int i   = lin >> 3;                       // 0..63
  const int m0  = (c8 * 4 + (i & 3)) * 128;
  const int n0  = (i >> 2) * 64;
  gemm_bt_t<2>(ain, wo, m0, n0, As, Bs, acc);

  const int t = threadIdx.x, lane = t & 63, w = t >> 6;
  const int wm = (w >> 1) * 64, wn = (w & 1) * 32;
  const int i16 = lane & 15, q4 = lane >> 4;
#pragma unroll
  for (int ft = 0; ft < 2; ++ft) {
    const int nb0 = n0 + wn + ft * 16 + (q4 << 2);
#pragma unroll
    for (int tt = 0; tt < 4; ++tt) {
      const int m = m0 + wm + tt * 16 + i16;
      float4 v;
      v.x = acc[ft][tt][0]; v.y = acc[ft][tt][1];
      v.z = acc[ft][tt][2]; v.w = acc[ft][tt][3];
      *(float4*)(out + (size_t)m * D_MODEL + nb0) = v;
    }
  }
}

// ---------------------------------------------------------------------------
extern "C" void kernel_launch(void* const* d_in, const int* in_sizes, int n_in,
                              void* d_out, int out_size, void* d_ws, size_t ws_size,
                              hipStream_t stream) {
  const void* x    = d_in[0];
  const void* wqkv = d_in[2];
  const void* wo   = d_in[3];
  float* out = (float*)d_out;

  const size_t NTOK  = (size_t)NBATCH * SEQ * D_MODEL;  // 4,194,304 elements
  const size_t NWQKV = (size_t)3 * D_MODEL * D_MODEL;   // 3,145,728
  const size_t NWO   = (size_t)D_MODEL * D_MODEL;       // 1,048,576

  unsigned short* base = (unsigned short*)((char*)d_ws + 16);
  unsigned short* Qw = base;                 // NTOK
  unsigned short* Kw = Qw + NTOK;            // NTOK
  unsigned short* Vw = Kw + NTOK;            // NTOK (V^T layout [bh][d][s])
  unsigned short* Aw = Vw + NTOK;            // NTOK (aliases xb; xb dead before attn writes)
  unsigned short* xb = Aw;                   // canonical bf16 x
  unsigned short* wq = Aw + NTOK;            // NWQKV

  dim3 blk(256);

  // Workspace for a SEPARATE wb (no aliasing) needs:
  const size_t need = 16 + (4 * NTOK + NWQKV + NWO) * sizeof(unsigned short);

  if (ws_size >= need) {
    // Single canonicalization dispatch: x + wqkv + wo.
    unsigned short* wb = wq + NWQKV;
    hipLaunchKernelGGL(cvt3_kernel, dim3(4096), blk, 0, stream,
                       x, xb, (int)(NTOK / 8), wqkv, wq, (int)(NWQKV / 8),
                       wo, wb);

    dim3 g1(32, 24);
    hipLaunchKernelGGL(qkv_rope_kernel, g1, blk, 0, stream, xb, wq, Qw, Kw, Vw);

    dim3 g2(SEQ / 128, NBATCH * NHEADS);
    hipLaunchKernelGGL(attn_mfma_kernel, g2, blk, 0, stream, Qw, Kw, Vw, Aw);

    dim3 g3(32, 16);
    hipLaunchKernelGGL(oproj_kernel, g3, blk, 0, stream, Aw, wb, out);
  } else {
    // Fallback: wb aliases wq, converted after qkv.
    unsigned short* wb = wq;
    hipLaunchKernelGGL(cvt2_kernel, dim3(3584), blk, 0, stream,
                       x, xb, (int)(NTOK / 8), wqkv, wq, (int)(NWQKV / 8));

    dim3 g1(32, 24);
    hipLaunchKernelGGL(qkv_rope_kernel, g1, blk, 0, stream, xb, wq, Qw, Kw, Vw);

    dim3 g2(SEQ / 128, NBATCH * NHEADS);
    hipLaunchKernelGGL(attn_mfma_kernel, g2, blk, 0, stream, Qw, Kw, Vw, Aw);

    hipLaunchKernelGGL(cvt2_kernel, dim3(512), blk, 0, stream,
                       wo, wb, (int)(NWO / 8), wo, wb, 0);

    dim3 g3(32, 16);
    hipLaunchKernelGGL(oproj_kernel, g3, blk, 0, stream, Aw, wb, out);
  }
}